// Round 1
// baseline (313.050 us; speedup 1.0000x reference)
//
#include <hip/hip_runtime.h>

// XL-attention: out = (softmax(Qh Kh^T / 8) Vh) @ Wc^T + bc
// L=2048, B=2, M=2048 -> J=4096, D=1024, H=16, Dh=64.
// All matmuls in bf16 MFMA (16x16x32), f32 accumulate.

using short8 = __attribute__((ext_vector_type(8))) short;
using f32x4  = __attribute__((ext_vector_type(4))) float;

#define DEV __device__ __forceinline__

DEV unsigned short f2bf(float f) {
  union { float f; unsigned int u; } x; x.f = f;
  unsigned int r = x.u + 0x7FFFu + ((x.u >> 16) & 1u);
  return (unsigned short)(r >> 16);
}

DEV void gload_lds16(const unsigned short* g, unsigned short* l) {
  __builtin_amdgcn_global_load_lds(
      (const __attribute__((address_space(1))) unsigned int*)g,
      (__attribute__((address_space(3))) unsigned int*)l, 16, 0, 0);
}

DEV float qmax16(float v) {
  v = fmaxf(v, __shfl_xor(v, 1));
  v = fmaxf(v, __shfl_xor(v, 2));
  v = fmaxf(v, __shfl_xor(v, 4));
  v = fmaxf(v, __shfl_xor(v, 8));
  return v;
}
DEV float qsum16(float v) {
  v += __shfl_xor(v, 1);
  v += __shfl_xor(v, 2);
  v += __shfl_xor(v, 4);
  v += __shfl_xor(v, 8);
  return v;
}

// ---------------------------------------------------------------------------
// f32 -> bf16 conversion of all inputs (q, concat(mem,kv), 4 weights)
// 8 elems / thread. Segment boundaries in 8-elem units.
__global__ __launch_bounds__(256) void convert_all(
    const float* __restrict__ q, const float* __restrict__ mem_,
    const float* __restrict__ kv, const float* __restrict__ wq,
    const float* __restrict__ wk, const float* __restrict__ wv,
    const float* __restrict__ wc, unsigned short* __restrict__ a_bf,
    unsigned short* __restrict__ c_bf, unsigned short* __restrict__ w_bf) {
  size_t u = (size_t)blockIdx.x * 256 + threadIdx.x;
  const float* src;
  unsigned short* dst;
  if (u < 524288u)        { src = q    + u * 8;                dst = a_bf + u * 8; }
  else if (u < 1048576u)  { src = mem_ + (u - 524288u) * 8;    dst = c_bf + (u - 524288u) * 8; }
  else if (u < 1572864u)  { src = kv   + (u - 1048576u) * 8;   dst = c_bf + 4194304u + (u - 1048576u) * 8; }
  else if (u < 1703936u)  { src = wq   + (u - 1572864u) * 8;   dst = w_bf + (u - 1572864u) * 8; }
  else if (u < 1835008u)  { src = wk   + (u - 1703936u) * 8;   dst = w_bf + 1048576u + (u - 1703936u) * 8; }
  else if (u < 1966080u)  { src = wv   + (u - 1835008u) * 8;   dst = w_bf + 2097152u + (u - 1835008u) * 8; }
  else                    { src = wc   + (u - 1966080u) * 8;   dst = w_bf + 3145728u + (u - 1966080u) * 8; }
  float4 v0 = ((const float4*)src)[0];
  float4 v1 = ((const float4*)src)[1];
  union { unsigned short us[8]; uint4 v; } o;
  o.us[0] = f2bf(v0.x); o.us[1] = f2bf(v0.y); o.us[2] = f2bf(v0.z); o.us[3] = f2bf(v0.w);
  o.us[4] = f2bf(v1.x); o.us[5] = f2bf(v1.y); o.us[6] = f2bf(v1.z); o.us[7] = f2bf(v1.w);
  *(uint4*)dst = o.v;
}

// ---------------------------------------------------------------------------
// C[M,1024] = A[M,1024] x Bw[1024,1024]^T (+bias). A,Bw bf16 row-major,
// Bw is [out_feat][in_feat] (torch Linear weight) == [N][K].
// 128x128 tile, BK=64, 4 waves, 16x16x32 MFMA.
// LDS rows are 128B: XOR-swizzle 16B slots (slot ^= row&7); global_load_lds
// writes linearly, so the global SOURCE column is pre-swizzled (rule #21).
// MODE 0: f32 out row-major (+bias)
// MODE 1: bf16 (acc+bias)*0.125 -> qh[b][n][i][d]     (row=i*2+b, col=n*64+d)
// MODE 2: bf16 (acc+bias)      -> kh[b][n][j][d]      (row=j*2+b)
// MODE 3: bf16 (acc+bias)      -> vt[b][n][d][j]      (transposed V)
template <int MODE>
__global__ __launch_bounds__(256, 2) void gemm_bt(
    const unsigned short* __restrict__ A, const unsigned short* __restrict__ Bw,
    const float* __restrict__ bias, void* __restrict__ outp) {
  __shared__ __align__(16) unsigned short lA[128 * 64];
  __shared__ __align__(16) unsigned short lB[128 * 64];
  const int tid = threadIdx.x;
  const int lane = tid & 63;
  const int w = tid >> 6;
  const int wr = w >> 1, wcn = w & 1;
  const int tm = blockIdx.x * 128;
  const int tn = blockIdx.y * 128;

  const int srow = lane >> 3;                 // row within 8-row chunk
  const int scol = ((lane & 7) ^ srow) * 8;   // pre-swizzled source column
  const unsigned short* aptr = A + (size_t)(tm + 32 * w + srow) * 1024 + scol;
  const unsigned short* bptr = Bw + (size_t)(tn + 32 * w + srow) * 1024 + scol;
  unsigned short* lAw = &lA[(32 * w) * 64];
  unsigned short* lBw = &lB[(32 * w) * 64];

  const f32x4 zero = {0.f, 0.f, 0.f, 0.f};
  f32x4 acc[4][4];
#pragma unroll
  for (int i = 0; i < 4; ++i)
#pragma unroll
    for (int j = 0; j < 4; ++j) acc[i][j] = zero;

  for (int kb = 0; kb < 16; ++kb) {
    const int ko = kb * 64;
#pragma unroll
    for (int c = 0; c < 4; ++c) {
      gload_lds16(aptr + ko + c * 8 * 1024, lAw + c * 8 * 64);
      gload_lds16(bptr + ko + c * 8 * 1024, lBw + c * 8 * 64);
    }
    __syncthreads();
#pragma unroll
    for (int kk = 0; kk < 2; ++kk) {
      short8 af[4], bfr[4];
#pragma unroll
      for (int mi = 0; mi < 4; ++mi) {
        int r = 64 * wr + 16 * mi + (lane & 15);
        int slot = (kk * 4 + (lane >> 4)) ^ (r & 7);
        af[mi] = *(const short8*)&lA[r * 64 + slot * 8];
      }
#pragma unroll
      for (int ni = 0; ni < 4; ++ni) {
        int r = 64 * wcn + 16 * ni + (lane & 15);
        int slot = (kk * 4 + (lane >> 4)) ^ (r & 7);
        bfr[ni] = *(const short8*)&lB[r * 64 + slot * 8];
      }
#pragma unroll
      for (int mi = 0; mi < 4; ++mi)
#pragma unroll
        for (int ni = 0; ni < 4; ++ni)
          acc[mi][ni] = __builtin_amdgcn_mfma_f32_16x16x32_bf16(
              af[mi], bfr[ni], acc[mi][ni], 0, 0, 0);
    }
    __syncthreads();
  }

  // Epilogue. C/D frag: row = (lane>>4)*4 + reg, col = lane&15.
  const int g4 = (lane >> 4) * 4;
  const int c0 = lane & 15;
#pragma unroll
  for (int mi = 0; mi < 4; ++mi) {
#pragma unroll
    for (int ni = 0; ni < 4; ++ni) {
      const int colt = tn + 64 * wcn + 16 * ni + c0;
      const float bv = bias[colt];
#pragma unroll
      for (int j = 0; j < 4; ++j) {
        const int rowt = tm + 64 * wr + 16 * mi + g4 + j;
        const float v = acc[mi][ni][j] + bv;
        if constexpr (MODE == 0) {
          ((float*)outp)[(size_t)rowt * 1024 + colt] = v;
        } else if constexpr (MODE == 1) {
          const int i = rowt >> 1, b = rowt & 1, n = colt >> 6, d = colt & 63;
          ((unsigned short*)outp)[(((size_t)(b * 16 + n) * 2048 + i) << 6) + d] =
              f2bf(v * 0.125f);  // fold 1/sqrt(Dh)=1/8 into Q
        } else if constexpr (MODE == 2) {
          const int jj = rowt >> 1, b = rowt & 1, n = colt >> 6, d = colt & 63;
          ((unsigned short*)outp)[(((size_t)(b * 16 + n) * 4096 + jj) << 6) + d] = f2bf(v);
        } else {
          const int jj = rowt >> 1, b = rowt & 1, n = colt >> 6, d = colt & 63;
          ((unsigned short*)outp)[((size_t)(b * 16 + n) * 64 + d) * 4096 + jj] = f2bf(v);
        }
      }
    }
  }
}

// ---------------------------------------------------------------------------
// Flash attention. Block = (head, 128-row q-tile), 4 waves x 32 q-rows.
// qh[b][n][i][64] (pre-scaled by 1/8), kh[b][n][j][64], vt[b][n][64][j].
// Per j-tile (64): S = Q K^T (MFMA) -> online softmax -> P via per-wave LDS
// (C-layout -> A-layout) -> O += P V (MFMA, B-operand = vt rows).
__global__ __launch_bounds__(256, 2) void attn_kernel(
    const unsigned short* __restrict__ qh, const unsigned short* __restrict__ kh,
    const unsigned short* __restrict__ vt, unsigned short* __restrict__ vec) {
  __shared__ __align__(16) unsigned short kl[64 * 64];
  __shared__ __align__(16) unsigned short vl[64 * 64];
  __shared__ __align__(16) unsigned short pl[4][32 * 64];
  const int tid = threadIdx.x;
  const int lane = tid & 63;
  const int w = tid >> 6;
  const int head = blockIdx.y;  // b*16 + n
  const int qt = blockIdx.x;
  const int b = head >> 4, n = head & 15;
  const unsigned short* qbase = qh + ((size_t)head * 2048 + qt * 128 + 32 * w) * 64;
  const unsigned short* kbase = kh + (size_t)head * 4096 * 64;
  const unsigned short* vbase = vt + (size_t)head * 64 * 4096;

  short8 qf[2][2];
#pragma unroll
  for (int mi = 0; mi < 2; ++mi)
#pragma unroll
    for (int kk = 0; kk < 2; ++kk)
      qf[mi][kk] = *(const short8*)&qbase[(16 * mi + (lane & 15)) * 64 + kk * 32 + (lane >> 4) * 8];

  const f32x4 zero = {0.f, 0.f, 0.f, 0.f};
  f32x4 oacc[2][4];
#pragma unroll
  for (int mi = 0; mi < 2; ++mi)
#pragma unroll
    for (int nd = 0; nd < 4; ++nd) oacc[mi][nd] = zero;
  float mrow[2][4], lrow[2][4];
#pragma unroll
  for (int mi = 0; mi < 2; ++mi)
#pragma unroll
    for (int j = 0; j < 4; ++j) { mrow[mi][j] = -3.0e38f; lrow[mi][j] = 0.f; }

  const int srow = lane >> 3;
  const int scol = ((lane & 7) ^ srow) * 8;
  unsigned short* pw = &pl[w][0];

  for (int jt = 0; jt < 64; ++jt) {
    const unsigned short* kt = kbase + jt * 64 * 64;
#pragma unroll
    for (int c = 0; c < 2; ++c) {
      const int r = 16 * w + 8 * c;
      gload_lds16(kt + (r + srow) * 64 + scol, &kl[r * 64]);
      gload_lds16(vbase + (size_t)(r + srow) * 4096 + jt * 64 + scol, &vl[r * 64]);
    }
    __syncthreads();

    // S = Q K^T  (Q pre-scaled by 1/8)
    f32x4 s[2][4];
#pragma unroll
    for (int mi = 0; mi < 2; ++mi)
#pragma unroll
      for (int nj = 0; nj < 4; ++nj) s[mi][nj] = zero;
#pragma unroll
    for (int kk = 0; kk < 2; ++kk) {
      short8 bk[4];
#pragma unroll
      for (int nj = 0; nj < 4; ++nj) {
        int r = 16 * nj + (lane & 15);
        int slot = (kk * 4 + (lane >> 4)) ^ (r & 7);
        bk[nj] = *(const short8*)&kl[r * 64 + slot * 8];
      }
#pragma unroll
      for (int mi = 0; mi < 2; ++mi)
#pragma unroll
        for (int nj = 0; nj < 4; ++nj)
          s[mi][nj] = __builtin_amdgcn_mfma_f32_16x16x32_bf16(qf[mi][kk], bk[nj], s[mi][nj], 0, 0, 0);
    }

    // online softmax; row r of C-frag lives in reg r&3 of lanes [16*(r>>2)..+15]
#pragma unroll
    for (int mi = 0; mi < 2; ++mi) {
#pragma unroll
      for (int j = 0; j < 4; ++j) {
        float t0 = fmaxf(fmaxf(s[mi][0][j], s[mi][1][j]), fmaxf(s[mi][2][j], s[mi][3][j]));
        t0 = qmax16(t0);
        const float mold = mrow[mi][j];
        const float mnew = fmaxf(mold, t0);
        const float sc = __expf(mold - mnew);
        mrow[mi][j] = mnew;
        float rs = 0.f;
#pragma unroll
        for (int nj = 0; nj < 4; ++nj) {
          float e = __expf(s[mi][nj][j] - mnew);
          s[mi][nj][j] = e;
          rs += e;
        }
        rs = qsum16(rs);
        lrow[mi][j] = lrow[mi][j] * sc + rs;
#pragma unroll
        for (int nd = 0; nd < 4; ++nd) oacc[mi][nd][j] *= sc;
      }
    }

    // pack P (C-layout) into per-wave swizzled LDS
#pragma unroll
    for (int mi = 0; mi < 2; ++mi)
#pragma unroll
      for (int nj = 0; nj < 4; ++nj)
#pragma unroll
        for (int j = 0; j < 4; ++j) {
          const int r = 16 * mi + (lane >> 4) * 4 + j;
          const int col = 16 * nj + (lane & 15);
          pw[r * 64 + (((col >> 3) ^ (r & 7)) * 8) + (col & 7)] = f2bf(s[mi][nj][j]);
        }

    // O += P V : A = P (rows=i), B = vt rows (rows=d), contraction over j
#pragma unroll
    for (int kk2 = 0; kk2 < 2; ++kk2) {
      short8 pa[2], bv[4];
#pragma unroll
      for (int mi = 0; mi < 2; ++mi) {
        int r = 16 * mi + (lane & 15);
        int slot = (kk2 * 4 + (lane >> 4)) ^ (r & 7);
        pa[mi] = *(const short8*)&pw[r * 64 + slot * 8];
      }
#pragma unroll
      for (int nd = 0; nd < 4; ++nd) {
        int r = 16 * nd + (lane & 15);
        int slot = (kk2 * 4 + (lane >> 4)) ^ (r & 7);
        bv[nd] = *(const short8*)&vl[r * 64 + slot * 8];
      }
#pragma unroll
      for (int mi = 0; mi < 2; ++mi)
#pragma unroll
        for (int nd = 0; nd < 4; ++nd)
          oacc[mi][nd] = __builtin_amdgcn_mfma_f32_16x16x32_bf16(pa[mi], bv[nd], oacc[mi][nd], 0, 0, 0);
    }
    __syncthreads();
  }

  // epilogue: vec[(i*2+b)*1024 + n*64+d] = O / l
  const int g4 = (lane >> 4) * 4;
#pragma unroll
  for (int mi = 0; mi < 2; ++mi)
#pragma unroll
    for (int j = 0; j < 4; ++j) {
      const float inv = 1.f / lrow[mi][j];
      const int i = qt * 128 + 32 * w + 16 * mi + g4 + j;
#pragma unroll
      for (int nd = 0; nd < 4; ++nd) {
        const int d = 16 * nd + (lane & 15);
        vec[(size_t)(i * 2 + b) * 1024 + n * 64 + d] = f2bf(oacc[mi][nd][j] * inv);
      }
    }
}

// ---------------------------------------------------------------------------
extern "C" void kernel_launch(void* const* d_in, const int* in_sizes, int n_in,
                              void* d_out, int out_size, void* d_ws, size_t ws_size,
                              hipStream_t stream) {
  (void)in_sizes; (void)n_in; (void)out_size; (void)ws_size;
  const float* q    = (const float*)d_in[0];
  const float* kv   = (const float*)d_in[1];
  const float* mem_ = (const float*)d_in[2];
  const float* wq   = (const float*)d_in[3];
  const float* bq   = (const float*)d_in[4];
  const float* wk   = (const float*)d_in[5];
  const float* bk   = (const float*)d_in[6];
  const float* wv   = (const float*)d_in[7];
  const float* bv   = (const float*)d_in[8];
  const float* wc   = (const float*)d_in[9];
  const float* bc   = (const float*)d_in[10];

  char* ws = (char*)d_ws;
  unsigned short* w_bf = (unsigned short*)(ws);                       // 8 MB: wq,wk,wv,wc
  unsigned short* a_bf = (unsigned short*)(ws + (8ull << 20));        // 8 MB: q bf16 [4096][1024]
  unsigned short* c_bf = (unsigned short*)(ws + (16ull << 20));       // 16 MB: concat(mem,kv) bf16 [8192][1024]
  unsigned short* qhb  = (unsigned short*)(ws + (32ull << 20));       // 8 MB: [b][n][2048][64]
  unsigned short* khb  = (unsigned short*)(ws + (40ull << 20));       // 16 MB: [b][n][4096][64]
  unsigned short* vtb  = (unsigned short*)(ws + (56ull << 20));       // 16 MB: [b][n][64][4096]
  unsigned short* vecb = a_bf;  // reuse (a_bf dead after Q projection)

  convert_all<<<8192, 256, 0, stream>>>(q, mem_, kv, wq, wk, wv, wc, a_bf, c_bf, w_bf);
  gemm_bt<1><<<dim3(32, 8), 256, 0, stream>>>(a_bf, w_bf,                bq, qhb);
  gemm_bt<2><<<dim3(64, 8), 256, 0, stream>>>(c_bf, w_bf + (1u << 20),   bk, khb);
  gemm_bt<3><<<dim3(64, 8), 256, 0, stream>>>(c_bf, w_bf + (2u << 20),   bv, vtb);
  attn_kernel<<<dim3(16, 32), 256, 0, stream>>>(qhb, khb, vtb, vecb);
  gemm_bt<0><<<dim3(32, 8), 256, 0, stream>>>(vecb, w_bf + (3u << 20),   bc, d_out);
}

// Round 2
// 221.928 us; speedup vs baseline: 1.4106x; 1.4106x over previous
//
#include <hip/hip_runtime.h>

// XL-attention: out = (softmax(Qh Kh^T / 8) Vh) @ Wc^T + bc
// L=2048, B=2, M=2048 -> J=4096, D=1024, H=16, Dh=64.
// All matmuls in bf16 MFMA (16x16x32), f32 accumulate.
// Attention uses swapped QK^T (S^T = K Q^T) so softmax is in-register,
// P stays in registers (k-slot permutation pi), exp2-direct scores.

using short8 = __attribute__((ext_vector_type(8))) short;
using f32x4  = __attribute__((ext_vector_type(4))) float;

#define DEV __device__ __forceinline__

DEV unsigned short f2bf(float f) {
  union { float f; unsigned int u; } x; x.f = f;
  unsigned int r = x.u + 0x7FFFu + ((x.u >> 16) & 1u);
  return (unsigned short)(r >> 16);
}

DEV unsigned int cvtpk(float lo, float hi) {
  unsigned int r;
  asm("v_cvt_pk_bf16_f32 %0, %1, %2" : "=v"(r) : "v"(lo), "v"(hi));
  return r;
}

DEV void gload_lds16(const unsigned short* g, unsigned short* l) {
  __builtin_amdgcn_global_load_lds(
      (const __attribute__((address_space(1))) unsigned int*)g,
      (__attribute__((address_space(3))) unsigned int*)l, 16, 0, 0);
}

// ---------------------------------------------------------------------------
// f32 -> bf16 conversion of all inputs (q, concat(mem,kv), 4 weights)
__global__ __launch_bounds__(256) void convert_all(
    const float* __restrict__ q, const float* __restrict__ mem_,
    const float* __restrict__ kv, const float* __restrict__ wq,
    const float* __restrict__ wk, const float* __restrict__ wv,
    const float* __restrict__ wc, unsigned short* __restrict__ a_bf,
    unsigned short* __restrict__ c_bf, unsigned short* __restrict__ w_bf) {
  size_t u = (size_t)blockIdx.x * 256 + threadIdx.x;
  const float* src;
  unsigned short* dst;
  if (u < 524288u)        { src = q    + u * 8;                dst = a_bf + u * 8; }
  else if (u < 1048576u)  { src = mem_ + (u - 524288u) * 8;    dst = c_bf + (u - 524288u) * 8; }
  else if (u < 1572864u)  { src = kv   + (u - 1048576u) * 8;   dst = c_bf + 4194304u + (u - 1048576u) * 8; }
  else if (u < 1703936u)  { src = wq   + (u - 1572864u) * 8;   dst = w_bf + (u - 1572864u) * 8; }
  else if (u < 1835008u)  { src = wk   + (u - 1703936u) * 8;   dst = w_bf + 1048576u + (u - 1703936u) * 8; }
  else if (u < 1966080u)  { src = wv   + (u - 1835008u) * 8;   dst = w_bf + 2097152u + (u - 1835008u) * 8; }
  else                    { src = wc   + (u - 1966080u) * 8;   dst = w_bf + 3145728u + (u - 1966080u) * 8; }
  float4 v0 = ((const float4*)src)[0];
  float4 v1 = ((const float4*)src)[1];
  union { unsigned short us[8]; uint4 v; } o;
  o.us[0] = f2bf(v0.x); o.us[1] = f2bf(v0.y); o.us[2] = f2bf(v0.z); o.us[3] = f2bf(v0.w);
  o.us[4] = f2bf(v1.x); o.us[5] = f2bf(v1.y); o.us[6] = f2bf(v1.z); o.us[7] = f2bf(v1.w);
  *(uint4*)dst = o.v;
}

// ---------------------------------------------------------------------------
// C[M,1024] = A[M,1024] x Bw[1024,1024]^T (+bias). Bw is [N][K] (torch Linear).
// 128x128 tile, BK=64, 4 waves, 16x16x32 MFMA, XOR-swizzled LDS (rule #21:
// pre-swizzled global source + swizzled ds_read).
// MODE 0: f32 out row-major (+bias)
// MODE 1: bf16 (acc+bias)*0.125*log2e -> qh[b][n][i][d]  (scores in log2 units)
// MODE 2: bf16 (acc+bias)            -> kh[b][n][j][d]
// MODE 3: bf16 (acc+bias)            -> vt[b][n][d][j]   (transposed V)
template <int MODE>
__global__ __launch_bounds__(256, 2) void gemm_bt(
    const unsigned short* __restrict__ A, const unsigned short* __restrict__ Bw,
    const float* __restrict__ bias, void* __restrict__ outp) {
  __shared__ __align__(16) unsigned short lA[128 * 64];
  __shared__ __align__(16) unsigned short lB[128 * 64];
  const int tid = threadIdx.x;
  const int lane = tid & 63;
  const int w = tid >> 6;
  const int wr = w >> 1, wcn = w & 1;
  const int tm = blockIdx.x * 128;
  const int tn = blockIdx.y * 128;

  const int srow = lane >> 3;
  const int scol = ((lane & 7) ^ srow) * 8;
  const unsigned short* aptr = A + (size_t)(tm + 32 * w + srow) * 1024 + scol;
  const unsigned short* bptr = Bw + (size_t)(tn + 32 * w + srow) * 1024 + scol;
  unsigned short* lAw = &lA[(32 * w) * 64];
  unsigned short* lBw = &lB[(32 * w) * 64];

  const f32x4 zero = {0.f, 0.f, 0.f, 0.f};
  f32x4 acc[4][4];
#pragma unroll
  for (int i = 0; i < 4; ++i)
#pragma unroll
    for (int j = 0; j < 4; ++j) acc[i][j] = zero;

  for (int kb = 0; kb < 16; ++kb) {
    const int ko = kb * 64;
#pragma unroll
    for (int c = 0; c < 4; ++c) {
      gload_lds16(aptr + ko + c * 8 * 1024, lAw + c * 8 * 64);
      gload_lds16(bptr + ko + c * 8 * 1024, lBw + c * 8 * 64);
    }
    __syncthreads();
#pragma unroll
    for (int kk = 0; kk < 2; ++kk) {
      short8 af[4], bfr[4];
#pragma unroll
      for (int mi = 0; mi < 4; ++mi) {
        int r = 64 * wr + 16 * mi + (lane & 15);
        int slot = (kk * 4 + (lane >> 4)) ^ (r & 7);
        af[mi] = *(const short8*)&lA[r * 64 + slot * 8];
      }
#pragma unroll
      for (int ni = 0; ni < 4; ++ni) {
        int r = 64 * wcn + 16 * ni + (lane & 15);
        int slot = (kk * 4 + (lane >> 4)) ^ (r & 7);
        bfr[ni] = *(const short8*)&lB[r * 64 + slot * 8];
      }
#pragma unroll
      for (int mi = 0; mi < 4; ++mi)
#pragma unroll
        for (int ni = 0; ni < 4; ++ni)
          acc[mi][ni] = __builtin_amdgcn_mfma_f32_16x16x32_bf16(
              af[mi], bfr[ni], acc[mi][ni], 0, 0, 0);
    }
    __syncthreads();
  }

  const int g4 = (lane >> 4) * 4;
  const int c0 = lane & 15;
#pragma unroll
  for (int mi = 0; mi < 4; ++mi) {
#pragma unroll
    for (int ni = 0; ni < 4; ++ni) {
      const int colt = tn + 64 * wcn + 16 * ni + c0;
      const float bv = bias[colt];
#pragma unroll
      for (int j = 0; j < 4; ++j) {
        const int rowt = tm + 64 * wr + 16 * mi + g4 + j;
        const float v = acc[mi][ni][j] + bv;
        if constexpr (MODE == 0) {
          ((float*)outp)[(size_t)rowt * 1024 + colt] = v;
        } else if constexpr (MODE == 1) {
          const int i = rowt >> 1, b = rowt & 1, n = colt >> 6, d = colt & 63;
          ((unsigned short*)outp)[(((size_t)(b * 16 + n) * 2048 + i) << 6) + d] =
              f2bf(v * 0.1803368801111f);  // 1/8 * log2(e): exp2-direct scores
        } else if constexpr (MODE == 2) {
          const int jj = rowt >> 1, b = rowt & 1, n = colt >> 6, d = colt & 63;
          ((unsigned short*)outp)[(((size_t)(b * 16 + n) * 4096 + jj) << 6) + d] = f2bf(v);
        } else {
          const int jj = rowt >> 1, b = rowt & 1, n = colt >> 6, d = colt & 63;
          ((unsigned short*)outp)[((size_t)(b * 16 + n) * 64 + d) * 4096 + jj] = f2bf(v);
        }
      }
    }
  }
}

// ---------------------------------------------------------------------------
// Flash attention, swapped-QK^T in-register-softmax structure.
// Block = (head, 128-row q-tile), 4 waves x 32 q-rows. K/V double-buffered,
// one barrier per j-tile. S^T = mfma(K,Q): lane holds 16 scores of column
// i=lane&15. P packed lane-locally via k-slot permutation
// pi(8g+e) = 4g+(e&3)+16(e>>2)+32*kk2 shared by P(A) and V(B) fragments.
__global__ __launch_bounds__(256, 2) void attn_kernel(
    const unsigned short* __restrict__ qh, const unsigned short* __restrict__ kh,
    const unsigned short* __restrict__ vt, unsigned short* __restrict__ vec) {
  __shared__ __align__(16) unsigned short kl[2][64 * 64];
  __shared__ __align__(16) unsigned short vl[2][64 * 64];
  const int tid = threadIdx.x;
  const int lane = tid & 63;
  const int w = tid >> 6;
  const int g = lane >> 4;
  const int l4 = lane & 15;
  const int head = blockIdx.y;  // b*16 + n
  const int qt = blockIdx.x;
  const int b = head >> 4, n = head & 15;
  const unsigned short* qbase = qh + ((size_t)head * 2048 + qt * 128 + 32 * w) * 64;
  const unsigned short* kbase = kh + (size_t)head * 4096 * 64;
  const unsigned short* vbase = vt + (size_t)head * 64 * 4096;

  // Q fragment (A-layout of Q == B-layout of Q^T, bit-identical)
  short8 qf[2][2];
#pragma unroll
  for (int mi = 0; mi < 2; ++mi)
#pragma unroll
    for (int kk = 0; kk < 2; ++kk)
      qf[mi][kk] = *(const short8*)&qbase[(16 * mi + l4) * 64 + kk * 32 + g * 8];

  const f32x4 zero = {0.f, 0.f, 0.f, 0.f};
  f32x4 oacc[2][4];
#pragma unroll
  for (int mi = 0; mi < 2; ++mi)
#pragma unroll
    for (int nd = 0; nd < 4; ++nd) oacc[mi][nd] = zero;
  float mrow[2] = {-3.0e38f, -3.0e38f};  // per lane: running max of column i=l4 (log2 units)
  float lrow[2] = {0.f, 0.f};

  const int srow = lane >> 3;
  const int scol = ((lane & 7) ^ srow) * 8;

  auto stage = [&](int jt, int bufi) {
#pragma unroll
    for (int c = 0; c < 2; ++c) {
      const int r = 16 * w + 8 * c;
      gload_lds16(kbase + (size_t)(jt * 64 + r + srow) * 64 + scol, &kl[bufi][r * 64]);
      gload_lds16(vbase + (size_t)(r + srow) * 4096 + jt * 64 + scol, &vl[bufi][r * 64]);
    }
  };

  stage(0, 0);
  __syncthreads();

  for (int jt = 0; jt < 64; ++jt) {
    const int buf = jt & 1;
    if (jt < 63) stage(jt + 1, buf ^ 1);  // prefetch next tile (issued before compute)

    // S^T[j][i] = mfma(A=K rows, B=Q^T): lane holds j=16nj+4g+reg, i=16mi+l4
    f32x4 s[2][4];
#pragma unroll
    for (int mi = 0; mi < 2; ++mi)
#pragma unroll
      for (int nj = 0; nj < 4; ++nj) s[mi][nj] = zero;
#pragma unroll
    for (int kk = 0; kk < 2; ++kk) {
      short8 bk[4];
#pragma unroll
      for (int nj = 0; nj < 4; ++nj) {
        int r = 16 * nj + l4;
        int slot = (kk * 4 + g) ^ (r & 7);
        bk[nj] = *(const short8*)&kl[buf][r * 64 + slot * 8];
      }
#pragma unroll
      for (int mi = 0; mi < 2; ++mi)
#pragma unroll
        for (int nj = 0; nj < 4; ++nj)
          s[mi][nj] = __builtin_amdgcn_mfma_f32_16x16x32_bf16(bk[nj], qf[mi][kk], s[mi][nj], 0, 0, 0);
    }

    // online softmax per column i=l4 (all in-lane + 2 shfl_xor)
#pragma unroll
    for (int mi = 0; mi < 2; ++mi) {
      float a0 = fmaxf(fmaxf(s[mi][0][0], s[mi][0][1]), fmaxf(s[mi][0][2], s[mi][0][3]));
      float a1 = fmaxf(fmaxf(s[mi][1][0], s[mi][1][1]), fmaxf(s[mi][1][2], s[mi][1][3]));
      float a2 = fmaxf(fmaxf(s[mi][2][0], s[mi][2][1]), fmaxf(s[mi][2][2], s[mi][2][3]));
      float a3 = fmaxf(fmaxf(s[mi][3][0], s[mi][3][1]), fmaxf(s[mi][3][2], s[mi][3][3]));
      float pmax = fmaxf(fmaxf(a0, a1), fmaxf(a2, a3));
      pmax = fmaxf(pmax, __shfl_xor(pmax, 16));
      pmax = fmaxf(pmax, __shfl_xor(pmax, 32));
      if (!__all(pmax <= mrow[mi] + 8.f)) {  // defer-max (T13), log2 units
        const float mnew = fmaxf(mrow[mi], pmax);
        const float sc = __builtin_amdgcn_exp2f(mrow[mi] - mnew);
        mrow[mi] = mnew;
        lrow[mi] *= sc;
        // broadcast sc from column-holders (lane i) to row-holders (rows 4g+reg)
#pragma unroll
        for (int reg = 0; reg < 4; ++reg) {
          const float scr = __shfl(sc, 4 * g + reg);
#pragma unroll
          for (int nd = 0; nd < 4; ++nd) oacc[mi][nd][reg] *= scr;
        }
      }
      const float m = mrow[mi];
      float rs = 0.f;
#pragma unroll
      for (int nj = 0; nj < 4; ++nj)
#pragma unroll
        for (int reg = 0; reg < 4; ++reg) {
          const float p = __builtin_amdgcn_exp2f(s[mi][nj][reg] - m);
          s[mi][nj][reg] = p;
          rs += p;
        }
      rs += __shfl_xor(rs, 16);
      rs += __shfl_xor(rs, 32);
      lrow[mi] += rs;
    }

    // pack P lane-locally: slot e of chunk kk2 -> j = 4g+(e&3)+16(e>>2)+32kk2
    short8 pa[2][2];
#pragma unroll
    for (int mi = 0; mi < 2; ++mi)
#pragma unroll
      for (int kk2 = 0; kk2 < 2; ++kk2) {
        union { unsigned int u[4]; short8 v; } t;
#pragma unroll
        for (int wd = 0; wd < 4; ++wd) {
          const int nj = (wd >> 1) + 2 * kk2;
          const int r0 = (wd & 1) * 2;
          t.u[wd] = cvtpk(s[mi][nj][r0], s[mi][nj][r0 + 1]);
        }
        pa[mi][kk2] = t.v;
      }

    // O += P V with permuted k-slots; V B-frag = two ds_read_b64 per fragment
#pragma unroll
    for (int kk2 = 0; kk2 < 2; ++kk2) {
      short8 bv4[4];
#pragma unroll
      for (int nd = 0; nd < 4; ++nd) {
        const int r = 16 * nd + l4;
        const int rx = r & 7;
        const int jA = 32 * kk2 + 4 * g;
        const int jB = jA + 16;
        union { unsigned int u[4]; short8 v; } t;
        *(uint2*)&t.u[0] = *(const uint2*)&vl[buf][r * 64 + (((jA >> 3) ^ rx) * 8) + (jA & 7)];
        *(uint2*)&t.u[2] = *(const uint2*)&vl[buf][r * 64 + (((jB >> 3) ^ rx) * 8) + (jB & 7)];
        bv4[nd] = t.v;
      }
#pragma unroll
      for (int mi = 0; mi < 2; ++mi)
#pragma unroll
        for (int nd = 0; nd < 4; ++nd)
          oacc[mi][nd] = __builtin_amdgcn_mfma_f32_16x16x32_bf16(pa[mi][kk2], bv4[nd], oacc[mi][nd], 0, 0, 0);
    }
    __syncthreads();  // single barrier: protects buf reuse + drains prefetch
  }

  // epilogue: O rows i=4g+reg need l from column-holder lanes
#pragma unroll
  for (int mi = 0; mi < 2; ++mi) {
#pragma unroll
    for (int reg = 0; reg < 4; ++reg) {
      const float lr = __shfl(lrow[mi], 4 * g + reg);
      const float inv = 1.f / lr;
      const int i = qt * 128 + 32 * w + 16 * mi + 4 * g + reg;
#pragma unroll
      for (int nd = 0; nd < 4; ++nd) {
        const int d = 16 * nd + l4;
        vec[(size_t)(i * 2 + b) * 1024 + n * 64 + d] = f2bf(oacc[mi][nd][reg] * inv);
      }
    }
  }
}

// ---------------------------------------------------------------------------
extern "C" void kernel_launch(void* const* d_in, const int* in_sizes, int n_in,
                              void* d_out, int out_size, void* d_ws, size_t ws_size,
                              hipStream_t stream) {
  (void)in_sizes; (void)n_in; (void)out_size; (void)ws_size;
  const float* q    = (const float*)d_in[0];
  const float* kv   = (const float*)d_in[1];
  const float* mem_ = (const float*)d_in[2];
  const float* wq   = (const float*)d_in[3];
  const float* bq   = (const float*)d_in[4];
  const float* wk   = (const float*)d_in[5];
  const float* bk   = (const float*)d_in[6];
  const float* wv   = (const float*)d_in[7];
  const float* bv   = (const float*)d_in[8];
  const float* wc   = (const float*)d_in[9];
  const float* bc   = (const float*)d_in[10];

  char* ws = (char*)d_ws;
  unsigned short* w_bf = (unsigned short*)(ws);                       // 8 MB: wq,wk,wv,wc
  unsigned short* a_bf = (unsigned short*)(ws + (8ull << 20));        // 8 MB: q bf16 [4096][1024]
  unsigned short* c_bf = (unsigned short*)(ws + (16ull << 20));       // 16 MB: concat(mem,kv)
  unsigned short* qhb  = (unsigned short*)(ws + (32ull << 20));       // 8 MB: [b][n][2048][64]
  unsigned short* khb  = (unsigned short*)(ws + (40ull << 20));       // 16 MB: [b][n][4096][64]
  unsigned short* vtb  = (unsigned short*)(ws + (56ull << 20));       // 16 MB: [b][n][64][4096]
  unsigned short* vecb = a_bf;  // reuse (a_bf dead after Q projection)

  convert_all<<<8192, 256, 0, stream>>>(q, mem_, kv, wq, wk, wv, wc, a_bf, c_bf, w_bf);
  gemm_bt<1><<<dim3(32, 8), 256, 0, stream>>>(a_bf, w_bf,                bq, qhb);
  gemm_bt<2><<<dim3(64, 8), 256, 0, stream>>>(c_bf, w_bf + (1u << 20),   bk, khb);
  gemm_bt<3><<<dim3(64, 8), 256, 0, stream>>>(c_bf, w_bf + (2u << 20),   bv, vtb);
  attn_kernel<<<dim3(16, 32), 256, 0, stream>>>(qhb, khb, vtb, vecb);
  gemm_bt<0><<<dim3(32, 8), 256, 0, stream>>>(vecb, w_bf + (3u << 20),   bc, d_out);
}

// Round 3
// 210.333 us; speedup vs baseline: 1.4884x; 1.0551x over previous
//
#include <hip/hip_runtime.h>

// XL-attention: out = (softmax(Qh Kh^T / 8) Vh) @ Wc^T + bc
// L=2048, B=2, M=2048 -> J=4096, D=1024, H=16, Dh=64.
// All matmuls in bf16 MFMA (16x16x32), f32 accumulate.
// Attention: swapped QK^T (S^T = K Q^T), in-register softmax, in-register P
// (k-slot permutation pi), exp2-direct scores, 64-row q-tiles (4 blocks/CU),
// XCD-grouped heads, V rows pre-permuted so PV B-frag is one ds_read_b128.

using short8 = __attribute__((ext_vector_type(8))) short;
using f32x4  = __attribute__((ext_vector_type(4))) float;

#define DEV __device__ __forceinline__

DEV unsigned short f2bf(float f) {
  union { float f; unsigned int u; } x; x.f = f;
  unsigned int r = x.u + 0x7FFFu + ((x.u >> 16) & 1u);
  return (unsigned short)(r >> 16);
}

DEV unsigned int cvtpk(float lo, float hi) {
  unsigned int r;
  asm("v_cvt_pk_bf16_f32 %0, %1, %2" : "=v"(r) : "v"(lo), "v"(hi));
  return r;
}

DEV void gload_lds16(const unsigned short* g, unsigned short* l) {
  __builtin_amdgcn_global_load_lds(
      (const __attribute__((address_space(1))) unsigned int*)g,
      (__attribute__((address_space(3))) unsigned int*)l, 16, 0, 0);
}

// ---------------------------------------------------------------------------
// f32 -> bf16 conversion of all inputs (q, concat(mem,kv), 4 weights)
__global__ __launch_bounds__(256) void convert_all(
    const float* __restrict__ q, const float* __restrict__ mem_,
    const float* __restrict__ kv, const float* __restrict__ wq,
    const float* __restrict__ wk, const float* __restrict__ wv,
    const float* __restrict__ wc, unsigned short* __restrict__ a_bf,
    unsigned short* __restrict__ c_bf, unsigned short* __restrict__ w_bf) {
  size_t u = (size_t)blockIdx.x * 256 + threadIdx.x;
  const float* src;
  unsigned short* dst;
  if (u < 524288u)        { src = q    + u * 8;                dst = a_bf + u * 8; }
  else if (u < 1048576u)  { src = mem_ + (u - 524288u) * 8;    dst = c_bf + (u - 524288u) * 8; }
  else if (u < 1572864u)  { src = kv   + (u - 1048576u) * 8;   dst = c_bf + 4194304u + (u - 1048576u) * 8; }
  else if (u < 1703936u)  { src = wq   + (u - 1572864u) * 8;   dst = w_bf + (u - 1572864u) * 8; }
  else if (u < 1835008u)  { src = wk   + (u - 1703936u) * 8;   dst = w_bf + 1048576u + (u - 1703936u) * 8; }
  else if (u < 1966080u)  { src = wv   + (u - 1835008u) * 8;   dst = w_bf + 2097152u + (u - 1835008u) * 8; }
  else                    { src = wc   + (u - 1966080u) * 8;   dst = w_bf + 3145728u + (u - 1966080u) * 8; }
  float4 v0 = ((const float4*)src)[0];
  float4 v1 = ((const float4*)src)[1];
  union { unsigned short us[8]; uint4 v; } o;
  o.us[0] = f2bf(v0.x); o.us[1] = f2bf(v0.y); o.us[2] = f2bf(v0.z); o.us[3] = f2bf(v0.w);
  o.us[4] = f2bf(v1.x); o.us[5] = f2bf(v1.y); o.us[6] = f2bf(v1.z); o.us[7] = f2bf(v1.w);
  *(uint4*)dst = o.v;
}

// ---------------------------------------------------------------------------
// C[M,1024] = A[M,1024] x Bw[1024,1024]^T (+bias). Bw is [N][K] (torch Linear).
// 128x128 tile, BK=64, 4 waves, 16x16x32 MFMA, XOR-swizzled LDS (rule #21).
// MODE 0: f32 out row-major (+bias)
// MODE 1: bf16 (acc+bias)*0.125*log2e -> qh[b][n][i][d]  (scores in log2 units)
// MODE 2: bf16 (acc+bias)            -> kh[b][n][j][d]
// MODE 3: bf16 (acc+bias)            -> vt[b][n][d][pi(j)]  (transposed V,
//         j permuted within each 64-group so attn PV frag is one b128 read)
template <int MODE>
__global__ __launch_bounds__(256, 2) void gemm_bt(
    const unsigned short* __restrict__ A, const unsigned short* __restrict__ Bw,
    const float* __restrict__ bias, void* __restrict__ outp) {
  __shared__ __align__(16) unsigned short lA[128 * 64];
  __shared__ __align__(16) unsigned short lB[128 * 64];
  const int tid = threadIdx.x;
  const int lane = tid & 63;
  const int w = tid >> 6;
  const int wr = w >> 1, wcn = w & 1;
  const int tm = blockIdx.x * 128;
  const int tn = blockIdx.y * 128;

  const int srow = lane >> 3;
  const int scol = ((lane & 7) ^ srow) * 8;
  const unsigned short* aptr = A + (size_t)(tm + 32 * w + srow) * 1024 + scol;
  const unsigned short* bptr = Bw + (size_t)(tn + 32 * w + srow) * 1024 + scol;
  unsigned short* lAw = &lA[(32 * w) * 64];
  unsigned short* lBw = &lB[(32 * w) * 64];

  const f32x4 zero = {0.f, 0.f, 0.f, 0.f};
  f32x4 acc[4][4];
#pragma unroll
  for (int i = 0; i < 4; ++i)
#pragma unroll
    for (int j = 0; j < 4; ++j) acc[i][j] = zero;

  for (int kb = 0; kb < 16; ++kb) {
    const int ko = kb * 64;
#pragma unroll
    for (int c = 0; c < 4; ++c) {
      gload_lds16(aptr + ko + c * 8 * 1024, lAw + c * 8 * 64);
      gload_lds16(bptr + ko + c * 8 * 1024, lBw + c * 8 * 64);
    }
    __syncthreads();
#pragma unroll
    for (int kk = 0; kk < 2; ++kk) {
      short8 af[4], bfr[4];
#pragma unroll
      for (int mi = 0; mi < 4; ++mi) {
        int r = 64 * wr + 16 * mi + (lane & 15);
        int slot = (kk * 4 + (lane >> 4)) ^ (r & 7);
        af[mi] = *(const short8*)&lA[r * 64 + slot * 8];
      }
#pragma unroll
      for (int ni = 0; ni < 4; ++ni) {
        int r = 64 * wcn + 16 * ni + (lane & 15);
        int slot = (kk * 4 + (lane >> 4)) ^ (r & 7);
        bfr[ni] = *(const short8*)&lB[r * 64 + slot * 8];
      }
#pragma unroll
      for (int mi = 0; mi < 4; ++mi)
#pragma unroll
        for (int ni = 0; ni < 4; ++ni)
          acc[mi][ni] = __builtin_amdgcn_mfma_f32_16x16x32_bf16(
              af[mi], bfr[ni], acc[mi][ni], 0, 0, 0);
    }
    __syncthreads();
  }

  const int g4 = (lane >> 4) * 4;
  const int c0 = lane & 15;
#pragma unroll
  for (int mi = 0; mi < 4; ++mi) {
#pragma unroll
    for (int ni = 0; ni < 4; ++ni) {
      const int colt = tn + 64 * wcn + 16 * ni + c0;
      const float bv = bias[colt];
#pragma unroll
      for (int j = 0; j < 4; ++j) {
        const int rowt = tm + 64 * wr + 16 * mi + g4 + j;
        const float v = acc[mi][ni][j] + bv;
        if constexpr (MODE == 0) {
          ((float*)outp)[(size_t)rowt * 1024 + colt] = v;
        } else if constexpr (MODE == 1) {
          const int i = rowt >> 1, b = rowt & 1, n = colt >> 6, d = colt & 63;
          ((unsigned short*)outp)[(((size_t)(b * 16 + n) * 2048 + i) << 6) + d] =
              f2bf(v * 0.1803368801111f);  // 1/8 * log2(e): exp2-direct scores
        } else if constexpr (MODE == 2) {
          const int jj = rowt >> 1, b = rowt & 1, n = colt >> 6, d = colt & 63;
          ((unsigned short*)outp)[(((size_t)(b * 16 + n) * 4096 + jj) << 6) + d] = f2bf(v);
        } else {
          const int jj = rowt >> 1, b = rowt & 1, n = colt >> 6, d = colt & 63;
          const int j6 = jj & 63;
          const int pos = (j6 & 3) | (((j6 >> 4) & 1) << 2) | (((j6 >> 2) & 3) << 3) |
                          (((j6 >> 5) & 1) << 5);
          ((unsigned short*)outp)[((size_t)(b * 16 + n) * 64 + d) * 4096 + (jj & ~63) + pos] =
              f2bf(v);
        }
      }
    }
  }
}

// ---------------------------------------------------------------------------
// Flash attention. Block = (head, 64-row q-tile): grid 1024 = 4 blocks/CU.
// 4 waves x 16 q-rows. K/V double-buffered, one barrier per j-tile.
// S^T = mfma(K,Q): lane holds 16 scores of column i=lane&15.
// P packed lane-locally; V pre-permuted so PV B-frag = one ds_read_b128.
// XCD swizzle: 4 heads per XCD (f&7 = xcd under n%8 round-robin).
__global__ __launch_bounds__(256, 4) void attn_kernel(
    const unsigned short* __restrict__ qh, const unsigned short* __restrict__ kh,
    const unsigned short* __restrict__ vt, unsigned short* __restrict__ vec) {
  __shared__ __align__(16) unsigned short kl[2][64 * 64];
  __shared__ __align__(16) unsigned short vl[2][64 * 64];
  const int tid = threadIdx.x;
  const int lane = tid & 63;
  const int w = tid >> 6;
  const int g = lane >> 4;
  const int l4 = lane & 15;
  // bijective remap: f = [head_hi(2) | qt(5) | xcd(3)] -> same-head blocks
  // land on one XCD (dispatch round-robins f%8 across 8 XCDs)
  const int f = blockIdx.x;
  const int qt = (f >> 3) & 31;
  const int head = (f & 7) * 4 + (f >> 8);
  const int b = head >> 4, n = head & 15;
  const unsigned short* qbase = qh + ((size_t)head * 2048 + qt * 64 + 16 * w) * 64;
  const unsigned short* kbase = kh + (size_t)head * 4096 * 64;
  const unsigned short* vbase = vt + (size_t)head * 64 * 4096;

  // Q fragment (A-layout of Q == B-layout of Q^T, bit-identical)
  short8 qf[2];
#pragma unroll
  for (int kk = 0; kk < 2; ++kk)
    qf[kk] = *(const short8*)&qbase[l4 * 64 + kk * 32 + g * 8];

  const f32x4 zero = {0.f, 0.f, 0.f, 0.f};
  f32x4 oacc[4];
#pragma unroll
  for (int nd = 0; nd < 4; ++nd) oacc[nd] = zero;
  float mrow = -3.0e38f;  // running max of column i=l4 (log2 units)
  float lrow = 0.f;

  const int srow = lane >> 3;
  const int scol = ((lane & 7) ^ srow) * 8;
  const unsigned short* kp0 = kbase + (size_t)(16 * w + srow) * 64 + scol;
  const unsigned short* kp1 = kbase + (size_t)(16 * w + 8 + srow) * 64 + scol;
  const unsigned short* vp0 = vbase + (size_t)(16 * w + srow) * 4096 + scol;
  const unsigned short* vp1 = vbase + (size_t)(16 * w + 8 + srow) * 4096 + scol;

  auto stage = [&](int jt, int bufi) {
    gload_lds16(kp0 + (size_t)jt * 4096, &kl[bufi][(16 * w) * 64]);
    gload_lds16(kp1 + (size_t)jt * 4096, &kl[bufi][(16 * w + 8) * 64]);
    gload_lds16(vp0 + jt * 64, &vl[bufi][(16 * w) * 64]);
    gload_lds16(vp1 + jt * 64, &vl[bufi][(16 * w + 8) * 64]);
  };

  stage(0, 0);
  __syncthreads();

  for (int jt = 0; jt < 64; ++jt) {
    const int buf = jt & 1;
    if (jt < 63) stage(jt + 1, buf ^ 1);  // prefetch next tile

    // S^T[j][i] = mfma(A=K rows, B=Q^T): lane holds j=16nj+4g+reg, i=l4
    f32x4 s[4];
#pragma unroll
    for (int nj = 0; nj < 4; ++nj) s[nj] = zero;
#pragma unroll
    for (int kk = 0; kk < 2; ++kk) {
      short8 bk[4];
#pragma unroll
      for (int nj = 0; nj < 4; ++nj) {
        int r = 16 * nj + l4;
        int slot = (kk * 4 + g) ^ (r & 7);
        bk[nj] = *(const short8*)&kl[buf][r * 64 + slot * 8];
      }
#pragma unroll
      for (int nj = 0; nj < 4; ++nj)
        s[nj] = __builtin_amdgcn_mfma_f32_16x16x32_bf16(bk[nj], qf[kk], s[nj], 0, 0, 0);
    }

    // online softmax per column i=l4 (in-lane tree + 2 shfl_xor)
    {
      float a0 = fmaxf(fmaxf(s[0][0], s[0][1]), fmaxf(s[0][2], s[0][3]));
      float a1 = fmaxf(fmaxf(s[1][0], s[1][1]), fmaxf(s[1][2], s[1][3]));
      float a2 = fmaxf(fmaxf(s[2][0], s[2][1]), fmaxf(s[2][2], s[2][3]));
      float a3 = fmaxf(fmaxf(s[3][0], s[3][1]), fmaxf(s[3][2], s[3][3]));
      float pmax = fmaxf(fmaxf(a0, a1), fmaxf(a2, a3));
      pmax = fmaxf(pmax, __shfl_xor(pmax, 16));
      pmax = fmaxf(pmax, __shfl_xor(pmax, 32));
      if (!__all(pmax <= mrow + 8.f)) {  // defer-max (T13), log2 units
        const float mnew = fmaxf(mrow, pmax);
        const float sc = __builtin_amdgcn_exp2f(mrow - mnew);
        mrow = mnew;
        lrow *= sc;
#pragma unroll
        for (int reg = 0; reg < 4; ++reg) {
          const float scr = __shfl(sc, 4 * g + reg);
#pragma unroll
          for (int nd = 0; nd < 4; ++nd) oacc[nd][reg] *= scr;
        }
      }
      const float m = mrow;
      float rs = 0.f;
#pragma unroll
      for (int nj = 0; nj < 4; ++nj)
#pragma unroll
        for (int reg = 0; reg < 4; ++reg) {
          const float p = __builtin_amdgcn_exp2f(s[nj][reg] - m);
          s[nj][reg] = p;
          rs += p;
        }
      rs += __shfl_xor(rs, 16);
      rs += __shfl_xor(rs, 32);
      lrow += rs;
    }

    // pack P lane-locally: slot e of chunk kk2 -> j = 4g+(e&3)+16(e>>2)+32kk2
    short8 pa[2];
#pragma unroll
    for (int kk2 = 0; kk2 < 2; ++kk2) {
      union { unsigned int u[4]; short8 v; } t;
#pragma unroll
      for (int wd = 0; wd < 4; ++wd) {
        const int nj = (wd >> 1) + 2 * kk2;
        const int r0 = (wd & 1) * 2;
        t.u[wd] = cvtpk(s[nj][r0], s[nj][r0 + 1]);
      }
      pa[kk2] = t.v;
    }

    // O += P V; V rows pre-permuted so the 8 k-slots of (g,kk2) are one
    // contiguous 16B block (index g+4kk2, XOR row swizzle) -> ds_read_b128
#pragma unroll
    for (int kk2 = 0; kk2 < 2; ++kk2) {
      short8 bv4[4];
#pragma unroll
      for (int nd = 0; nd < 4; ++nd) {
        const int r = 16 * nd + l4;
        const int blk = (g + 4 * kk2) ^ (r & 7);
        bv4[nd] = *(const short8*)&vl[buf][r * 64 + blk * 8];
      }
#pragma unroll
      for (int nd = 0; nd < 4; ++nd)
        oacc[nd] = __builtin_amdgcn_mfma_f32_16x16x32_bf16(pa[kk2], bv4[nd], oacc[nd], 0, 0, 0);
    }
    __syncthreads();  // single barrier: protects buf reuse + drains prefetch
  }

  // epilogue: O rows i=4g+reg need l from column-holder lanes
#pragma unroll
  for (int reg = 0; reg < 4; ++reg) {
    const float lr = __shfl(lrow, 4 * g + reg);
    const float inv = 1.f / lr;
    const int i = qt * 64 + 16 * w + 4 * g + reg;
#pragma unroll
    for (int nd = 0; nd < 4; ++nd) {
      const int d = 16 * nd + l4;
      vec[(size_t)(i * 2 + b) * 1024 + n * 64 + d] = f2bf(oacc[nd][reg] * inv);
    }
  }
}

// ---------------------------------------------------------------------------
extern "C" void kernel_launch(void* const* d_in, const int* in_sizes, int n_in,
                              void* d_out, int out_size, void* d_ws, size_t ws_size,
                              hipStream_t stream) {
  (void)in_sizes; (void)n_in; (void)out_size; (void)ws_size;
  const float* q    = (const float*)d_in[0];
  const float* kv   = (const float*)d_in[1];
  const float* mem_ = (const float*)d_in[2];
  const float* wq   = (const float*)d_in[3];
  const float* bq   = (const float*)d_in[4];
  const float* wk   = (const float*)d_in[5];
  const float* bk   = (const float*)d_in[6];
  const float* wv   = (const float*)d_in[7];
  const float* bv   = (const float*)d_in[8];
  const float* wc   = (const float*)d_in[9];
  const float* bc   = (const float*)d_in[10];

  char* ws = (char*)d_ws;
  unsigned short* w_bf = (unsigned short*)(ws);                       // 8 MB: wq,wk,wv,wc
  unsigned short* a_bf = (unsigned short*)(ws + (8ull << 20));        // 8 MB: q bf16 [4096][1024]
  unsigned short* c_bf = (unsigned short*)(ws + (16ull << 20));       // 16 MB: concat(mem,kv)
  unsigned short* qhb  = (unsigned short*)(ws + (32ull << 20));       // 8 MB: [b][n][2048][64]
  unsigned short* khb  = (unsigned short*)(ws + (40ull << 20));       // 16 MB: [b][n][4096][64]
  unsigned short* vtb  = (unsigned short*)(ws + (56ull << 20));       // 16 MB: [b][n][64][pi(j)]
  unsigned short* vecb = a_bf;  // reuse (a_bf dead after Q projection)

  convert_all<<<8192, 256, 0, stream>>>(q, mem_, kv, wq, wk, wv, wc, a_bf, c_bf, w_bf);
  gemm_bt<1><<<dim3(32, 8), 256, 0, stream>>>(a_bf, w_bf,                bq, qhb);
  gemm_bt<2><<<dim3(64, 8), 256, 0, stream>>>(c_bf, w_bf + (1u << 20),   bk, khb);
  gemm_bt<3><<<dim3(64, 8), 256, 0, stream>>>(c_bf, w_bf + (2u << 20),   bv, vtb);
  attn_kernel<<<1024, 256, 0, stream>>>(qhb, khb, vtb, vecb);
  gemm_bt<0><<<dim3(32, 8), 256, 0, stream>>>(vecb, w_bf + (3u << 20),   bc, d_out);
}

// Round 5
// 201.952 us; speedup vs baseline: 1.5501x; 1.0415x over previous
//
#include <hip/hip_runtime.h>

// XL-attention: out = (softmax(Qh Kh^T / 8) Vh) @ Wc^T + bc
// L=2048, B=2, M=2048 -> J=4096, D=1024, H=16, Dh=64.
// All matmuls in bf16 MFMA (16x16x32), f32 accumulate.
// Attention: swapped QK^T (S^T = K Q^T), in-register online softmax with
// defer-max (round-3-proven numerics: p = 2^(s-m) <= 2^8), in-register P,
// 8-wave blocks of 256 q-rows (32 rows/wave: 32 MFMAs per 16 LDS reads),
// 1 block/CU, XCD-grouped heads, V pre-permuted so PV B-frag = ds_read_b128.

using short8 = __attribute__((ext_vector_type(8))) short;
using f32x4  = __attribute__((ext_vector_type(4))) float;

#define DEV __device__ __forceinline__

DEV unsigned short f2bf(float f) {
  union { float f; unsigned int u; } x; x.f = f;
  unsigned int r = x.u + 0x7FFFu + ((x.u >> 16) & 1u);
  return (unsigned short)(r >> 16);
}

DEV unsigned int cvtpk(float lo, float hi) {
  unsigned int r;
  asm("v_cvt_pk_bf16_f32 %0, %1, %2" : "=v"(r) : "v"(lo), "v"(hi));
  return r;
}

DEV void gload_lds16(const unsigned short* g, unsigned short* l) {
  __builtin_amdgcn_global_load_lds(
      (const __attribute__((address_space(1))) unsigned int*)g,
      (__attribute__((address_space(3))) unsigned int*)l, 16, 0, 0);
}

// ---------------------------------------------------------------------------
// f32 -> bf16 conversion of all inputs (q, concat(mem,kv), 4 weights)
__global__ __launch_bounds__(256) void convert_all(
    const float* __restrict__ q, const float* __restrict__ mem_,
    const float* __restrict__ kv, const float* __restrict__ wq,
    const float* __restrict__ wk, const float* __restrict__ wv,
    const float* __restrict__ wc, unsigned short* __restrict__ a_bf,
    unsigned short* __restrict__ c_bf, unsigned short* __restrict__ w_bf) {
  size_t u = (size_t)blockIdx.x * 256 + threadIdx.x;
  const float* src;
  unsigned short* dst;
  if (u < 524288u)        { src = q    + u * 8;                dst = a_bf + u * 8; }
  else if (u < 1048576u)  { src = mem_ + (u - 524288u) * 8;    dst = c_bf + (u - 524288u) * 8; }
  else if (u < 1572864u)  { src = kv   + (u - 1048576u) * 8;   dst = c_bf + 4194304u + (u - 1048576u) * 8; }
  else if (u < 1703936u)  { src = wq   + (u - 1572864u) * 8;   dst = w_bf + (u - 1572864u) * 8; }
  else if (u < 1835008u)  { src = wk   + (u - 1703936u) * 8;   dst = w_bf + 1048576u + (u - 1703936u) * 8; }
  else if (u < 1966080u)  { src = wv   + (u - 1835008u) * 8;   dst = w_bf + 2097152u + (u - 1835008u) * 8; }
  else                    { src = wc   + (u - 1966080u) * 8;   dst = w_bf + 3145728u + (u - 1966080u) * 8; }
  float4 v0 = ((const float4*)src)[0];
  float4 v1 = ((const float4*)src)[1];
  union { unsigned short us[8]; uint4 v; } o;
  o.us[0] = f2bf(v0.x); o.us[1] = f2bf(v0.y); o.us[2] = f2bf(v0.z); o.us[3] = f2bf(v0.w);
  o.us[4] = f2bf(v1.x); o.us[5] = f2bf(v1.y); o.us[6] = f2bf(v1.z); o.us[7] = f2bf(v1.w);
  *(uint4*)dst = o.v;
}

// ---------------------------------------------------------------------------
// C[M,1024] = A[M,1024] x Bw[1024,1024]^T (+bias). Bw is [N][K] (torch Linear).
// 128x128 tile, BK=64, 4 waves, 16x16x32 MFMA, XOR-swizzled LDS (rule #21).
// MODE 0: f32 out row-major (+bias)
// MODE 1: bf16 (acc+bias)*0.125*log2e -> qh[b][n][i][d]  (scores in log2 units)
// MODE 2: bf16 (acc+bias)            -> kh[b][n][j][d]
// MODE 3: bf16 (acc+bias)            -> vt[b][n][d][pi(j)]  (transposed V,
//         j permuted within each 64-group so attn PV frag is one b128 read)
template <int MODE>
__global__ __launch_bounds__(256, 2) void gemm_bt(
    const unsigned short* __restrict__ A, const unsigned short* __restrict__ Bw,
    const float* __restrict__ bias, void* __restrict__ outp) {
  __shared__ __align__(16) unsigned short lA[128 * 64];
  __shared__ __align__(16) unsigned short lB[128 * 64];
  const int tid = threadIdx.x;
  const int lane = tid & 63;
  const int w = tid >> 6;
  const int wr = w >> 1, wcn = w & 1;
  const int tm = blockIdx.x * 128;
  const int tn = blockIdx.y * 128;

  const int srow = lane >> 3;
  const int scol = ((lane & 7) ^ srow) * 8;
  const unsigned short* aptr = A + (size_t)(tm + 32 * w + srow) * 1024 + scol;
  const unsigned short* bptr = Bw + (size_t)(tn + 32 * w + srow) * 1024 + scol;
  unsigned short* lAw = &lA[(32 * w) * 64];
  unsigned short* lBw = &lB[(32 * w) * 64];

  const f32x4 zero = {0.f, 0.f, 0.f, 0.f};
  f32x4 acc[4][4];
#pragma unroll
  for (int i = 0; i < 4; ++i)
#pragma unroll
    for (int j = 0; j < 4; ++j) acc[i][j] = zero;

  for (int kb = 0; kb < 16; ++kb) {
    const int ko = kb * 64;
#pragma unroll
    for (int c = 0; c < 4; ++c) {
      gload_lds16(aptr + ko + c * 8 * 1024, lAw + c * 8 * 64);
      gload_lds16(bptr + ko + c * 8 * 1024, lBw + c * 8 * 64);
    }
    __syncthreads();
#pragma unroll
    for (int kk = 0; kk < 2; ++kk) {
      short8 af[4], bfr[4];
#pragma unroll
      for (int mi = 0; mi < 4; ++mi) {
        int r = 64 * wr + 16 * mi + (lane & 15);
        int slot = (kk * 4 + (lane >> 4)) ^ (r & 7);
        af[mi] = *(const short8*)&lA[r * 64 + slot * 8];
      }
#pragma unroll
      for (int ni = 0; ni < 4; ++ni) {
        int r = 64 * wcn + 16 * ni + (lane & 15);
        int slot = (kk * 4 + (lane >> 4)) ^ (r & 7);
        bfr[ni] = *(const short8*)&lB[r * 64 + slot * 8];
      }
#pragma unroll
      for (int mi = 0; mi < 4; ++mi)
#pragma unroll
        for (int ni = 0; ni < 4; ++ni)
          acc[mi][ni] = __builtin_amdgcn_mfma_f32_16x16x32_bf16(
              af[mi], bfr[ni], acc[mi][ni], 0, 0, 0);
    }
    __syncthreads();
  }

  const int g4 = (lane >> 4) * 4;
  const int c0 = lane & 15;
#pragma unroll
  for (int mi = 0; mi < 4; ++mi) {
#pragma unroll
    for (int ni = 0; ni < 4; ++ni) {
      const int colt = tn + 64 * wcn + 16 * ni + c0;
      const float bv = bias[colt];
#pragma unroll
      for (int j = 0; j < 4; ++j) {
        const int rowt = tm + 64 * wr + 16 * mi + g4 + j;
        const float v = acc[mi][ni][j] + bv;
        if constexpr (MODE == 0) {
          ((float*)outp)[(size_t)rowt * 1024 + colt] = v;
        } else if constexpr (MODE == 1) {
          const int i = rowt >> 1, b = rowt & 1, n = colt >> 6, d = colt & 63;
          ((unsigned short*)outp)[(((size_t)(b * 16 + n) * 2048 + i) << 6) + d] =
              f2bf(v * 0.1803368801111f);  // 1/8 * log2(e): exp2-direct scores
        } else if constexpr (MODE == 2) {
          const int jj = rowt >> 1, b = rowt & 1, n = colt >> 6, d = colt & 63;
          ((unsigned short*)outp)[(((size_t)(b * 16 + n) * 4096 + jj) << 6) + d] = f2bf(v);
        } else {
          const int jj = rowt >> 1, b = rowt & 1, n = colt >> 6, d = colt & 63;
          const int j6 = jj & 63;
          const int pos = (j6 & 3) | (((j6 >> 4) & 1) << 2) | (((j6 >> 2) & 3) << 3) |
                          (((j6 >> 5) & 1) << 5);
          ((unsigned short*)outp)[((size_t)(b * 16 + n) * 64 + d) * 4096 + (jj & ~63) + pos] =
              f2bf(v);
        }
      }
    }
  }
}

// ---------------------------------------------------------------------------
// Flash attention. Block = (head, 256-row q-tile): 512 threads / 8 waves,
// 32 q-rows per wave (mi=0,1). Grid 256 = 1 block/CU. K/V double-buffered,
// one barrier per 64-j tile. S^T = mfma(K,Q): lane holds 16 scores of
// query column i=16mi+l4. Softmax = round-3-proven defer-max path
// (p = 2^(s-m), bounded by 2^8). V pre-permuted so PV B-frag is one
// ds_read_b128; bv4 shared across mi. XCD map: f&7 = xcd.
__global__ __launch_bounds__(512, 2) void attn_kernel(
    const unsigned short* __restrict__ qh, const unsigned short* __restrict__ kh,
    const unsigned short* __restrict__ vt, unsigned short* __restrict__ vec) {
  __shared__ __align__(16) unsigned short kl[2][64 * 64];
  __shared__ __align__(16) unsigned short vl[2][64 * 64];
  const int tid = threadIdx.x;
  const int lane = tid & 63;
  const int w = tid >> 6;  // 0..7
  const int g = lane >> 4;
  const int l4 = lane & 15;
  // f = [qt(3) | head_lo(2) | xcd(3)]: per XCD, 4 heads x 8 q-tiles
  const int f = blockIdx.x;
  const int head = (f & 7) * 4 + ((f >> 3) & 3);
  const int qt = f >> 5;  // 0..7
  const int b = head >> 4, n = head & 15;
  const unsigned short* qbase = qh + ((size_t)head * 2048 + qt * 256 + 32 * w) * 64;
  const unsigned short* kbase = kh + (size_t)head * 4096 * 64;
  const unsigned short* vbase = vt + (size_t)head * 64 * 4096;

  // Q fragments: 32 rows per wave (A-layout of Q == B-layout of Q^T)
  short8 qf[2][2];
#pragma unroll
  for (int mi = 0; mi < 2; ++mi)
#pragma unroll
    for (int kk = 0; kk < 2; ++kk)
      qf[mi][kk] = *(const short8*)&qbase[(16 * mi + l4) * 64 + kk * 32 + g * 8];

  const f32x4 zero = {0.f, 0.f, 0.f, 0.f};
  f32x4 oacc[2][4];
#pragma unroll
  for (int mi = 0; mi < 2; ++mi)
#pragma unroll
    for (int nd = 0; nd < 4; ++nd) oacc[mi][nd] = zero;
  float mrow[2] = {-3.0e38f, -3.0e38f};  // running max of col i=16mi+l4 (log2)
  float lrow[2] = {0.f, 0.f};            // full row denominator (reduced per tile)

  const int srow = lane >> 3;
  const int scol = ((lane & 7) ^ srow) * 8;
  // each wave stages 8 rows (1 KB) of K and of V per tile
  const unsigned short* kp = kbase + (size_t)(8 * w + srow) * 64 + scol;
  const unsigned short* vp = vbase + (size_t)(8 * w + srow) * 4096 + scol;

  auto stage = [&](int jt, int bufi) {
    gload_lds16(kp + (size_t)jt * 4096, &kl[bufi][(8 * w) * 64]);
    gload_lds16(vp + jt * 64, &vl[bufi][(8 * w) * 64]);
  };

  stage(0, 0);
  __syncthreads();

  for (int jt = 0; jt < 64; ++jt) {
    const int buf = jt & 1;
    if (jt < 63) stage(jt + 1, buf ^ 1);  // prefetch next tile

    // S^T[j][i] = mfma(A=K rows, B=Q^T): lane holds j=16nj+4g+reg, i=16mi+l4
    f32x4 s[2][4];
#pragma unroll
    for (int mi = 0; mi < 2; ++mi)
#pragma unroll
      for (int nj = 0; nj < 4; ++nj) s[mi][nj] = zero;
#pragma unroll
    for (int kk = 0; kk < 2; ++kk) {
      short8 bk[4];
#pragma unroll
      for (int nj = 0; nj < 4; ++nj) {
        int r = 16 * nj + l4;
        int slot = (kk * 4 + g) ^ (r & 7);
        bk[nj] = *(const short8*)&kl[buf][r * 64 + slot * 8];
      }
#pragma unroll
      for (int mi = 0; mi < 2; ++mi)
#pragma unroll
        for (int nj = 0; nj < 4; ++nj)
          s[mi][nj] = __builtin_amdgcn_mfma_f32_16x16x32_bf16(bk[nj], qf[mi][kk], s[mi][nj], 0, 0, 0);
    }

    // online softmax per column i=16mi+l4 — exact round-3 numerics per mi
    short8 pa[2][2];
#pragma unroll
    for (int mi = 0; mi < 2; ++mi) {
      float a0 = fmaxf(fmaxf(s[mi][0][0], s[mi][0][1]), fmaxf(s[mi][0][2], s[mi][0][3]));
      float a1 = fmaxf(fmaxf(s[mi][1][0], s[mi][1][1]), fmaxf(s[mi][1][2], s[mi][1][3]));
      float a2 = fmaxf(fmaxf(s[mi][2][0], s[mi][2][1]), fmaxf(s[mi][2][2], s[mi][2][3]));
      float a3 = fmaxf(fmaxf(s[mi][3][0], s[mi][3][1]), fmaxf(s[mi][3][2], s[mi][3][3]));
      float pmax = fmaxf(fmaxf(a0, a1), fmaxf(a2, a3));
      pmax = fmaxf(pmax, __shfl_xor(pmax, 16));
      pmax = fmaxf(pmax, __shfl_xor(pmax, 32));
      if (!__all(pmax <= mrow[mi] + 8.f)) {  // defer-max (T13), log2 units
        const float mnew = fmaxf(mrow[mi], pmax);
        const float sc = __builtin_amdgcn_exp2f(mrow[mi] - mnew);
        mrow[mi] = mnew;
        lrow[mi] *= sc;
        // broadcast sc from column-holder (lane i) to row-holders (rows 4g+reg)
#pragma unroll
        for (int reg = 0; reg < 4; ++reg) {
          const float scr = __shfl(sc, 4 * g + reg);
#pragma unroll
          for (int nd = 0; nd < 4; ++nd) oacc[mi][nd][reg] *= scr;
        }
      }
      const float m = mrow[mi];
      float rs = 0.f;
#pragma unroll
      for (int nj = 0; nj < 4; ++nj)
#pragma unroll
        for (int reg = 0; reg < 4; ++reg) {
          const float p = __builtin_amdgcn_exp2f(s[mi][nj][reg] - m);
          s[mi][nj][reg] = p;
          rs += p;
        }
      rs += __shfl_xor(rs, 16);
      rs += __shfl_xor(rs, 32);
      lrow[mi] += rs;
      // pack P lane-locally: slot e of chunk kk2 -> j = 4g+(e&3)+16(e>>2)+32kk2
#pragma unroll
      for (int kk2 = 0; kk2 < 2; ++kk2) {
        union { unsigned int u[4]; short8 v; } t;
#pragma unroll
        for (int wd = 0; wd < 4; ++wd) {
          const int nj = (wd >> 1) + 2 * kk2;
          const int r0 = (wd & 1) * 2;
          t.u[wd] = cvtpk(s[mi][nj][r0], s[mi][nj][r0 + 1]);
        }
        pa[mi][kk2] = t.v;
      }
    }

    // O += P V; V rows pre-permuted so the 8 k-slots of (g,kk2) are one
    // contiguous 16B block; bv4 shared by both mi (LDS amortization)
#pragma unroll
    for (int kk2 = 0; kk2 < 2; ++kk2) {
      short8 bv4[4];
#pragma unroll
      for (int nd = 0; nd < 4; ++nd) {
        const int r = 16 * nd + l4;
        const int blk = (g + 4 * kk2) ^ (r & 7);
        bv4[nd] = *(const short8*)&vl[buf][r * 64 + blk * 8];
      }
#pragma unroll
      for (int mi = 0; mi < 2; ++mi)
#pragma unroll
        for (int nd = 0; nd < 4; ++nd)
          oacc[mi][nd] = __builtin_amdgcn_mfma_f32_16x16x32_bf16(pa[mi][kk2], bv4[nd], oacc[mi][nd], 0, 0, 0);
    }
    __syncthreads();  // protects buf reuse + drains prefetch
  }

  // epilogue: lrow is already the full row sum; rows 4g+reg read it by shfl
#pragma unroll
  for (int mi = 0; mi < 2; ++mi) {
#pragma unroll
    for (int reg = 0; reg < 4; ++reg) {
      const float lr = __shfl(lrow[mi], 4 * g + reg);
      const float inv = 1.f / lr;
      const int i = qt * 256 + 32 * w + 16 * mi + 4 * g + reg;
#pragma unroll
      for (int nd = 0; nd < 4; ++nd) {
        const int d = 16 * nd + l4;
        vec[(size_t)(i * 2 + b) * 1024 + n * 64 + d] = f2bf(oacc[mi][nd][reg] * inv);
      }
    }
  }
}

// ---------------------------------------------------------------------------
extern "C" void kernel_launch(void* const* d_in, const int* in_sizes, int n_in,
                              void* d_out, int out_size, void* d_ws, size_t ws_size,
                              hipStream_t stream) {
  (void)in_sizes; (void)n_in; (void)out_size; (void)ws_size;
  const float* q    = (const float*)d_in[0];
  const float* kv   = (const float*)d_in[1];
  const float* mem_ = (const float*)d_in[2];
  const float* wq   = (const float*)d_in[3];
  const float* bq   = (const float*)d_in[4];
  const float* wk   = (const float*)d_in[5];
  const float* bk   = (const float*)d_in[6];
  const float* wv   = (const float*)d_in[7];
  const float* bv   = (const float*)d_in[8];
  const float* wc   = (const float*)d_in[9];
  const float* bc   = (const float*)d_in[10];

  char* ws = (char*)d_ws;
  unsigned short* w_bf = (unsigned short*)(ws);                       // 8 MB: wq,wk,wv,wc
  unsigned short* a_bf = (unsigned short*)(ws + (8ull << 20));        // 8 MB: q bf16 [4096][1024]
  unsigned short* c_bf = (unsigned short*)(ws + (16ull << 20));       // 16 MB: concat(mem,kv)
  unsigned short* qhb  = (unsigned short*)(ws + (32ull << 20));       // 8 MB: [b][n][2048][64]
  unsigned short* khb  = (unsigned short*)(ws + (40ull << 20));       // 16 MB: [b][n][4096][64]
  unsigned short* vtb  = (unsigned short*)(ws + (56ull << 20));       // 16 MB: [b][n][64][pi(j)]
  unsigned short* vecb = a_bf;  // reuse (a_bf dead after Q projection)

  convert_all<<<8192, 256, 0, stream>>>(q, mem_, kv, wq, wk, wv, wc, a_bf, c_bf, w_bf);
  gemm_bt<1><<<dim3(32, 8), 256, 0, stream>>>(a_bf, w_bf,                bq, qhb);
  gemm_bt<2><<<dim3(64, 8), 256, 0, stream>>>(c_bf, w_bf + (1u << 20),   bk, khb);
  gemm_bt<3><<<dim3(64, 8), 256, 0, stream>>>(c_bf, w_bf + (2u << 20),   bv, vtb);
  attn_kernel<<<256, 512, 0, stream>>>(qhb, khb, vtb, vecb);
  gemm_bt<0><<<dim3(32, 8), 256, 0, stream>>>(vecb, w_bf + (3u << 20),   bc, d_out);
}

// Round 6
// 198.722 us; speedup vs baseline: 1.5753x; 1.0163x over previous
//
#include <hip/hip_runtime.h>

// XL-attention: out = (softmax(Qh Kh^T / 8) Vh) @ Wc^T + bc
// L=2048, B=2, M=2048 -> J=4096, D=1024, H=16, Dh=64.
// All matmuls in bf16 MFMA (16x16x32), f32 accumulate.
// Attention: swapped QK^T (S^T = K Q^T), in-register online softmax with
// defer-max (proven numerics: p = 2^(s-m) <= 2^8), in-register P,
// 8-wave blocks of 128 q-rows, grid 512 = 2 blocks/CU (4 waves/SIMD),
// triple-buffered K/V with counted vmcnt(2) + raw s_barrier (loads stay in
// flight across barriers), XCD-grouped heads, V pre-permuted so the PV
// B-fragment is one ds_read_b128.

using short8 = __attribute__((ext_vector_type(8))) short;
using f32x4  = __attribute__((ext_vector_type(4))) float;

#define DEV __device__ __forceinline__

DEV unsigned short f2bf(float f) {
  union { float f; unsigned int u; } x; x.f = f;
  unsigned int r = x.u + 0x7FFFu + ((x.u >> 16) & 1u);
  return (unsigned short)(r >> 16);
}

DEV unsigned int cvtpk(float lo, float hi) {
  unsigned int r;
  asm("v_cvt_pk_bf16_f32 %0, %1, %2" : "=v"(r) : "v"(lo), "v"(hi));
  return r;
}

DEV void gload_lds16(const unsigned short* g, unsigned short* l) {
  __builtin_amdgcn_global_load_lds(
      (const __attribute__((address_space(1))) unsigned int*)g,
      (__attribute__((address_space(3))) unsigned int*)l, 16, 0, 0);
}

#define BARRIER_RAW()                      \
  do {                                     \
    __builtin_amdgcn_sched_barrier(0);     \
    __builtin_amdgcn_s_barrier();          \
    __builtin_amdgcn_sched_barrier(0);     \
  } while (0)

// ---------------------------------------------------------------------------
// f32 -> bf16 conversion of all inputs (q, concat(mem,kv), 4 weights)
__global__ __launch_bounds__(256) void convert_all(
    const float* __restrict__ q, const float* __restrict__ mem_,
    const float* __restrict__ kv, const float* __restrict__ wq,
    const float* __restrict__ wk, const float* __restrict__ wv,
    const float* __restrict__ wc, unsigned short* __restrict__ a_bf,
    unsigned short* __restrict__ c_bf, unsigned short* __restrict__ w_bf) {
  size_t u = (size_t)blockIdx.x * 256 + threadIdx.x;
  const float* src;
  unsigned short* dst;
  if (u < 524288u)        { src = q    + u * 8;                dst = a_bf + u * 8; }
  else if (u < 1048576u)  { src = mem_ + (u - 524288u) * 8;    dst = c_bf + (u - 524288u) * 8; }
  else if (u < 1572864u)  { src = kv   + (u - 1048576u) * 8;   dst = c_bf + 4194304u + (u - 1048576u) * 8; }
  else if (u < 1703936u)  { src = wq   + (u - 1572864u) * 8;   dst = w_bf + (u - 1572864u) * 8; }
  else if (u < 1835008u)  { src = wk   + (u - 1703936u) * 8;   dst = w_bf + 1048576u + (u - 1703936u) * 8; }
  else if (u < 1966080u)  { src = wv   + (u - 1835008u) * 8;   dst = w_bf + 2097152u + (u - 1835008u) * 8; }
  else                    { src = wc   + (u - 1966080u) * 8;   dst = w_bf + 3145728u + (u - 1966080u) * 8; }
  float4 v0 = ((const float4*)src)[0];
  float4 v1 = ((const float4*)src)[1];
  union { unsigned short us[8]; uint4 v; } o;
  o.us[0] = f2bf(v0.x); o.us[1] = f2bf(v0.y); o.us[2] = f2bf(v0.z); o.us[3] = f2bf(v0.w);
  o.us[4] = f2bf(v1.x); o.us[5] = f2bf(v1.y); o.us[6] = f2bf(v1.z); o.us[7] = f2bf(v1.w);
  *(uint4*)dst = o.v;
}

// ---------------------------------------------------------------------------
// C[M,1024] = A[M,1024] x Bw[1024,1024]^T (+bias). Bw is [N][K] (torch Linear).
// 128x128 tile, BK=64, 4 waves, 16x16x32 MFMA, XOR-swizzled LDS (rule #21).
// MODE 0: f32 out row-major (+bias)
// MODE 1: bf16 (acc+bias)*0.125*log2e -> qh[b][n][i][d]  (scores in log2 units)
// MODE 2: bf16 (acc+bias)            -> kh[b][n][j][d]
// MODE 3: bf16 (acc+bias)            -> vt[b][n][d][pi(j)]  (transposed V,
//         j permuted within each 64-group so attn PV frag is one b128 read)
template <int MODE>
__global__ __launch_bounds__(256, 2) void gemm_bt(
    const unsigned short* __restrict__ A, const unsigned short* __restrict__ Bw,
    const float* __restrict__ bias, void* __restrict__ outp) {
  __shared__ __align__(16) unsigned short lA[128 * 64];
  __shared__ __align__(16) unsigned short lB[128 * 64];
  const int tid = threadIdx.x;
  const int lane = tid & 63;
  const int w = tid >> 6;
  const int wr = w >> 1, wcn = w & 1;
  const int tm = blockIdx.x * 128;
  const int tn = blockIdx.y * 128;

  const int srow = lane >> 3;
  const int scol = ((lane & 7) ^ srow) * 8;
  const unsigned short* aptr = A + (size_t)(tm + 32 * w + srow) * 1024 + scol;
  const unsigned short* bptr = Bw + (size_t)(tn + 32 * w + srow) * 1024 + scol;
  unsigned short* lAw = &lA[(32 * w) * 64];
  unsigned short* lBw = &lB[(32 * w) * 64];

  const f32x4 zero = {0.f, 0.f, 0.f, 0.f};
  f32x4 acc[4][4];
#pragma unroll
  for (int i = 0; i < 4; ++i)
#pragma unroll
    for (int j = 0; j < 4; ++j) acc[i][j] = zero;

  for (int kb = 0; kb < 16; ++kb) {
    const int ko = kb * 64;
#pragma unroll
    for (int c = 0; c < 4; ++c) {
      gload_lds16(aptr + ko + c * 8 * 1024, lAw + c * 8 * 64);
      gload_lds16(bptr + ko + c * 8 * 1024, lBw + c * 8 * 64);
    }
    __syncthreads();
#pragma unroll
    for (int kk = 0; kk < 2; ++kk) {
      short8 af[4], bfr[4];
#pragma unroll
      for (int mi = 0; mi < 4; ++mi) {
        int r = 64 * wr + 16 * mi + (lane & 15);
        int slot = (kk * 4 + (lane >> 4)) ^ (r & 7);
        af[mi] = *(const short8*)&lA[r * 64 + slot * 8];
      }
#pragma unroll
      for (int ni = 0; ni < 4; ++ni) {
        int r = 64 * wcn + 16 * ni + (lane & 15);
        int slot = (kk * 4 + (lane >> 4)) ^ (r & 7);
        bfr[ni] = *(const short8*)&lB[r * 64 + slot * 8];
      }
#pragma unroll
      for (int mi = 0; mi < 4; ++mi)
#pragma unroll
        for (int ni = 0; ni < 4; ++ni)
          acc[mi][ni] = __builtin_amdgcn_mfma_f32_16x16x32_bf16(
              af[mi], bfr[ni], acc[mi][ni], 0, 0, 0);
    }
    __syncthreads();
  }

  const int g4 = (lane >> 4) * 4;
  const int c0 = lane & 15;
#pragma unroll
  for (int mi = 0; mi < 4; ++mi) {
#pragma unroll
    for (int ni = 0; ni < 4; ++ni) {
      const int colt = tn + 64 * wcn + 16 * ni + c0;
      const float bv = bias[colt];
#pragma unroll
      for (int j = 0; j < 4; ++j) {
        const int rowt = tm + 64 * wr + 16 * mi + g4 + j;
        const float v = acc[mi][ni][j] + bv;
        if constexpr (MODE == 0) {
          ((float*)outp)[(size_t)rowt * 1024 + colt] = v;
        } else if constexpr (MODE == 1) {
          const int i = rowt >> 1, b = rowt & 1, n = colt >> 6, d = colt & 63;
          ((unsigned short*)outp)[(((size_t)(b * 16 + n) * 2048 + i) << 6) + d] =
              f2bf(v * 0.1803368801111f);  // 1/8 * log2(e): exp2-direct scores
        } else if constexpr (MODE == 2) {
          const int jj = rowt >> 1, b = rowt & 1, n = colt >> 6, d = colt & 63;
          ((unsigned short*)outp)[(((size_t)(b * 16 + n) * 4096 + jj) << 6) + d] = f2bf(v);
        } else {
          const int jj = rowt >> 1, b = rowt & 1, n = colt >> 6, d = colt & 63;
          const int j6 = jj & 63;
          const int pos = (j6 & 3) | (((j6 >> 4) & 1) << 2) | (((j6 >> 2) & 3) << 3) |
                          (((j6 >> 5) & 1) << 5);
          ((unsigned short*)outp)[((size_t)(b * 16 + n) * 64 + d) * 4096 + (jj & ~63) + pos] =
              f2bf(v);
        }
      }
    }
  }
}

// ---------------------------------------------------------------------------
// Flash attention. Block = (head, 128-row q-tile): 512 threads / 8 waves,
// 16 q-rows per wave. Grid 512 = 2 blocks/CU (4 waves/SIMD).
// K/V TRIPLE-buffered; barriers are raw s_barrier preceded by counted
// s_waitcnt vmcnt(2): each wave issues exactly 2 global_load_lds per tile,
// so vmcnt(2) retires tile jt+1's loads while jt+2's stay in flight.
// S^T = mfma(K,Q): lane holds 16 scores of query column i=lane&15.
// V pre-permuted so PV B-frag is one ds_read_b128. XCD map: f&7 = xcd.
__global__ __launch_bounds__(512, 4) void attn_kernel(
    const unsigned short* __restrict__ qh, const unsigned short* __restrict__ kh,
    const unsigned short* __restrict__ vt, unsigned short* __restrict__ vec) {
  __shared__ __align__(16) unsigned short kl[3][64 * 64];
  __shared__ __align__(16) unsigned short vl[3][64 * 64];
  const int tid = threadIdx.x;
  const int lane = tid & 63;
  const int w = tid >> 6;  // 0..7
  const int g = lane >> 4;
  const int l4 = lane & 15;
  // f = [qt(4) | head_lo(2) | xcd(3)]: per XCD, 4 heads x 16 q-tiles
  const int f = blockIdx.x;
  const int head = (f & 7) * 4 + ((f >> 3) & 3);
  const int qt = f >> 5;  // 0..15
  const int b = head >> 4, n = head & 15;
  const unsigned short* qbase = qh + ((size_t)head * 2048 + qt * 128 + 16 * w) * 64;
  const unsigned short* kbase = kh + (size_t)head * 4096 * 64;
  const unsigned short* vbase = vt + (size_t)head * 64 * 4096;

  // Q fragment: 16 rows per wave (A-layout of Q == B-layout of Q^T)
  short8 qf[2];
#pragma unroll
  for (int kk = 0; kk < 2; ++kk)
    qf[kk] = *(const short8*)&qbase[l4 * 64 + kk * 32 + g * 8];

  const f32x4 zero = {0.f, 0.f, 0.f, 0.f};
  f32x4 oacc[4];
#pragma unroll
  for (int nd = 0; nd < 4; ++nd) oacc[nd] = zero;
  float mrow = -3.0e38f;  // running max of column i=l4 (log2 units)
  float lrow = 0.f;       // full row denominator (reduced per tile)

  const int srow = lane >> 3;
  const int scol = ((lane & 7) ^ srow) * 8;
  // each wave stages 8 rows (1 KB) of K and of V per tile: 2 vmem ops/tile
  const unsigned short* kp = kbase + (size_t)(8 * w + srow) * 64 + scol;
  const unsigned short* vp = vbase + (size_t)(8 * w + srow) * 4096 + scol;

  auto stage = [&](int jt, int bufi) {
    gload_lds16(kp + (size_t)jt * 4096, &kl[bufi][(8 * w) * 64]);
    gload_lds16(vp + jt * 64, &vl[bufi][(8 * w) * 64]);
  };

  // prologue: prefetch tiles 0 and 1; vmcnt(2) retires qf loads + tile 0
  stage(0, 0);
  stage(1, 1);
  asm volatile("s_waitcnt vmcnt(2)" ::: "memory");
  BARRIER_RAW();

  for (int jt = 0; jt < 64; ++jt) {
    const int buf = jt % 3;
    if (jt + 2 < 64) stage(jt + 2, (jt + 2) % 3);  // depth-2 prefetch

    // S^T[j][i] = mfma(A=K rows, B=Q^T): lane holds j=16nj+4g+reg, i=l4
    f32x4 s[4];
#pragma unroll
    for (int nj = 0; nj < 4; ++nj) s[nj] = zero;
#pragma unroll
    for (int kk = 0; kk < 2; ++kk) {
      short8 bk[4];
#pragma unroll
      for (int nj = 0; nj < 4; ++nj) {
        int r = 16 * nj + l4;
        int slot = (kk * 4 + g) ^ (r & 7);
        bk[nj] = *(const short8*)&kl[buf][r * 64 + slot * 8];
      }
#pragma unroll
      for (int nj = 0; nj < 4; ++nj)
        s[nj] = __builtin_amdgcn_mfma_f32_16x16x32_bf16(bk[nj], qf[kk], s[nj], 0, 0, 0);
    }

    // online softmax per column i=l4 (proven defer-max numerics)
    {
      float a0 = fmaxf(fmaxf(s[0][0], s[0][1]), fmaxf(s[0][2], s[0][3]));
      float a1 = fmaxf(fmaxf(s[1][0], s[1][1]), fmaxf(s[1][2], s[1][3]));
      float a2 = fmaxf(fmaxf(s[2][0], s[2][1]), fmaxf(s[2][2], s[2][3]));
      float a3 = fmaxf(fmaxf(s[3][0], s[3][1]), fmaxf(s[3][2], s[3][3]));
      float pmax = fmaxf(fmaxf(a0, a1), fmaxf(a2, a3));
      pmax = fmaxf(pmax, __shfl_xor(pmax, 16));
      pmax = fmaxf(pmax, __shfl_xor(pmax, 32));
      if (!__all(pmax <= mrow + 8.f)) {  // defer-max (T13), log2 units
        const float mnew = fmaxf(mrow, pmax);
        const float sc = __builtin_amdgcn_exp2f(mrow - mnew);
        mrow = mnew;
        lrow *= sc;
        // broadcast sc from column-holder (lane i) to row-holders (rows 4g+reg)
#pragma unroll
        for (int reg = 0; reg < 4; ++reg) {
          const float scr = __shfl(sc, 4 * g + reg);
#pragma unroll
          for (int nd = 0; nd < 4; ++nd) oacc[nd][reg] *= scr;
        }
      }
      const float m = mrow;
      float rs = 0.f;
#pragma unroll
      for (int nj = 0; nj < 4; ++nj)
#pragma unroll
        for (int reg = 0; reg < 4; ++reg) {
          const float p = __builtin_amdgcn_exp2f(s[nj][reg] - m);
          s[nj][reg] = p;
          rs += p;
        }
      rs += __shfl_xor(rs, 16);
      rs += __shfl_xor(rs, 32);
      lrow += rs;
    }

    // pack P lane-locally: slot e of chunk kk2 -> j = 4g+(e&3)+16(e>>2)+32kk2
    short8 pa[2];
#pragma unroll
    for (int kk2 = 0; kk2 < 2; ++kk2) {
      union { unsigned int u[4]; short8 v; } t;
#pragma unroll
      for (int wd = 0; wd < 4; ++wd) {
        const int nj = (wd >> 1) + 2 * kk2;
        const int r0 = (wd & 1) * 2;
        t.u[wd] = cvtpk(s[nj][r0], s[nj][r0 + 1]);
      }
      pa[kk2] = t.v;
    }

    // O += P V; V rows pre-permuted so the 8 k-slots of (g,kk2) are one
    // contiguous 16B block (index g+4kk2, XOR row swizzle) -> ds_read_b128
#pragma unroll
    for (int kk2 = 0; kk2 < 2; ++kk2) {
      short8 bv4[4];
#pragma unroll
      for (int nd = 0; nd < 4; ++nd) {
        const int r = 16 * nd + l4;
        const int blk = (g + 4 * kk2) ^ (r & 7);
        bv4[nd] = *(const short8*)&vl[buf][r * 64 + blk * 8];
      }
#pragma unroll
      for (int nd = 0; nd < 4; ++nd)
        oacc[nd] = __builtin_amdgcn_mfma_f32_16x16x32_bf16(pa[kk2], bv4[nd], oacc[nd], 0, 0, 0);
    }

    // counted-vmcnt barrier: tile jt+1's loads retired, jt+2's stay in flight
    if (jt < 63) {
      if (jt < 62) {
        asm volatile("s_waitcnt vmcnt(2)" ::: "memory");
      } else {
        asm volatile("s_waitcnt vmcnt(0)" ::: "memory");
      }
      BARRIER_RAW();
    }
  }

  // epilogue: lrow is the full row sum; rows 4g+reg read it by shfl
#pragma unroll
  for (int reg = 0; reg < 4; ++reg) {
    const float lr = __shfl(lrow, 4 * g + reg);
    const float inv = 1.f / lr;
    const int i = qt * 128 + 16 * w + 4 * g + reg;
#pragma unroll
    for (int nd = 0; nd < 4; ++nd) {
      const int d = 16 * nd + l4;
      vec[(size_t)(i * 2 + b) * 1024 + n * 64 + d] = f2bf(oacc[nd][reg] * inv);
    }
  }
}

// ---------------------------------------------------------------------------
extern "C" void kernel_launch(void* const* d_in, const int* in_sizes, int n_in,
                              void* d_out, int out_size, void* d_ws, size_t ws_size,
                              hipStream_t stream) {
  (void)in_sizes; (void)n_in; (void)out_size; (void)ws_size;
  const float* q    = (const float*)d_in[0];
  const float* kv   = (const float*)d_in[1];
  const float* mem_ = (const float*)d_in[2];
  const float* wq   = (const float*)d_in[3];
  const float* bq   = (const float*)d_in[4];
  const float* wk   = (const float*)d_in[5];
  const float* bk   = (const float*)d_in[6];
  const float* wv   = (const float*)d_in[7];
  const float* bv   = (const float*)d_in[8];
  const float* wc   = (const float*)d_in[9];
  const float* bc   = (const float*)d_in[10];

  char* ws = (char*)d_ws;
  unsigned short* w_bf = (unsigned short*)(ws);                       // 8 MB: wq,wk,wv,wc
  unsigned short* a_bf = (unsigned short*)(ws + (8ull << 20));        // 8 MB: q bf16 [4096][1024]
  unsigned short* c_bf = (unsigned short*)(ws + (16ull << 20));       // 16 MB: concat(mem,kv)
  unsigned short* qhb  = (unsigned short*)(ws + (32ull << 20));       // 8 MB: [b][n][2048][64]
  unsigned short* khb  = (unsigned short*)(ws + (40ull << 20));       // 16 MB: [b][n][4096][64]
  unsigned short* vtb  = (unsigned short*)(ws + (56ull << 20));       // 16 MB: [b][n][64][pi(j)]
  unsigned short* vecb = a_bf;  // reuse (a_bf dead after Q projection)

  convert_all<<<8192, 256, 0, stream>>>(q, mem_, kv, wq, wk, wv, wc, a_bf, c_bf, w_bf);
  gemm_bt<1><<<dim3(32, 8), 256, 0, stream>>>(a_bf, w_bf,                bq, qhb);
  gemm_bt<2><<<dim3(64, 8), 256, 0, stream>>>(c_bf, w_bf + (1u << 20),   bk, khb);
  gemm_bt<3><<<dim3(64, 8), 256, 0, stream>>>(c_bf, w_bf + (2u << 20),   bv, vtb);
  attn_kernel<<<512, 512, 0, stream>>>(qhb, khb, vtb, vecb);
  gemm_bt<0><<<dim3(32, 8), 256, 0, stream>>>(vecb, w_bf + (3u << 20),   bc, d_out);
}

// Round 7
// 195.556 us; speedup vs baseline: 1.6008x; 1.0162x over previous
//
#include <hip/hip_runtime.h>

// XL-attention: out = (softmax(Qh Kh^T / 8) Vh) @ Wc^T + bc
// L=2048, B=2, M=2048 -> J=4096, D=1024, H=16, Dh=64.
// All matmuls in bf16 MFMA (16x16x32), f32 accumulate.
// Attention: swapped QK^T (S^T = K Q^T), in-register online softmax with
// defer-max (proven numerics: p = 2^(s-m) <= 2^8), in-register P,
// 8-wave blocks of 128 q-rows, grid 512 = 2 blocks/CU (4 waves/SIMD).
// K/V staged as PAIRS of proven 64x64 sub-tiles, double-buffered: one
// vmcnt(0)+s_barrier per 128 j's (half the sync overhead), fully unrolled
// so all buffer indices are compile-time constants. s_setprio(1) around
// MFMA clusters (T5). V pre-permuted so the PV B-frag is one ds_read_b128.

using short8 = __attribute__((ext_vector_type(8))) short;
using f32x4  = __attribute__((ext_vector_type(4))) float;

#define DEV __device__ __forceinline__

DEV unsigned short f2bf(float f) {
  union { float f; unsigned int u; } x; x.f = f;
  unsigned int r = x.u + 0x7FFFu + ((x.u >> 16) & 1u);
  return (unsigned short)(r >> 16);
}

DEV unsigned int cvtpk(float lo, float hi) {
  unsigned int r;
  asm("v_cvt_pk_bf16_f32 %0, %1, %2" : "=v"(r) : "v"(lo), "v"(hi));
  return r;
}

DEV void gload_lds16(const unsigned short* g, unsigned short* l) {
  __builtin_amdgcn_global_load_lds(
      (const __attribute__((address_space(1))) unsigned int*)g,
      (__attribute__((address_space(3))) unsigned int*)l, 16, 0, 0);
}

#define BARRIER_RAW()                      \
  do {                                     \
    __builtin_amdgcn_sched_barrier(0);     \
    __builtin_amdgcn_s_barrier();          \
    __builtin_amdgcn_sched_barrier(0);     \
  } while (0)

// ---------------------------------------------------------------------------
// f32 -> bf16 conversion of all inputs (q, concat(mem,kv), 4 weights)
__global__ __launch_bounds__(256) void convert_all(
    const float* __restrict__ q, const float* __restrict__ mem_,
    const float* __restrict__ kv, const float* __restrict__ wq,
    const float* __restrict__ wk, const float* __restrict__ wv,
    const float* __restrict__ wc, unsigned short* __restrict__ a_bf,
    unsigned short* __restrict__ c_bf, unsigned short* __restrict__ w_bf) {
  size_t u = (size_t)blockIdx.x * 256 + threadIdx.x;
  const float* src;
  unsigned short* dst;
  if (u < 524288u)        { src = q    + u * 8;                dst = a_bf + u * 8; }
  else if (u < 1048576u)  { src = mem_ + (u - 524288u) * 8;    dst = c_bf + (u - 524288u) * 8; }
  else if (u < 1572864u)  { src = kv   + (u - 1048576u) * 8;   dst = c_bf + 4194304u + (u - 1048576u) * 8; }
  else if (u < 1703936u)  { src = wq   + (u - 1572864u) * 8;   dst = w_bf + (u - 1572864u) * 8; }
  else if (u < 1835008u)  { src = wk   + (u - 1703936u) * 8;   dst = w_bf + 1048576u + (u - 1703936u) * 8; }
  else if (u < 1966080u)  { src = wv   + (u - 1835008u) * 8;   dst = w_bf + 2097152u + (u - 1835008u) * 8; }
  else                    { src = wc   + (u - 1966080u) * 8;   dst = w_bf + 3145728u + (u - 1966080u) * 8; }
  float4 v0 = ((const float4*)src)[0];
  float4 v1 = ((const float4*)src)[1];
  union { unsigned short us[8]; uint4 v; } o;
  o.us[0] = f2bf(v0.x); o.us[1] = f2bf(v0.y); o.us[2] = f2bf(v0.z); o.us[3] = f2bf(v0.w);
  o.us[4] = f2bf(v1.x); o.us[5] = f2bf(v1.y); o.us[6] = f2bf(v1.z); o.us[7] = f2bf(v1.w);
  *(uint4*)dst = o.v;
}

// ---------------------------------------------------------------------------
// C[M,1024] = A[M,1024] x Bw[1024,1024]^T (+bias). Bw is [N][K] (torch Linear).
// 128x128 tile, BK=64, 4 waves, 16x16x32 MFMA, XOR-swizzled LDS (rule #21).
// MODE 0: f32 out row-major (+bias)
// MODE 1: bf16 (acc+bias)*0.125*log2e -> qh[b][n][i][d]  (scores in log2 units)
// MODE 2: bf16 (acc+bias)            -> kh[b][n][j][d]
// MODE 3: bf16 (acc+bias)            -> vt[b][n][d][pi(j)]  (transposed V,
//         j permuted within each 64-group so attn PV frag is one b128 read)
template <int MODE>
__global__ __launch_bounds__(256, 2) void gemm_bt(
    const unsigned short* __restrict__ A, const unsigned short* __restrict__ Bw,
    const float* __restrict__ bias, void* __restrict__ outp) {
  __shared__ __align__(16) unsigned short lA[128 * 64];
  __shared__ __align__(16) unsigned short lB[128 * 64];
  const int tid = threadIdx.x;
  const int lane = tid & 63;
  const int w = tid >> 6;
  const int wr = w >> 1, wcn = w & 1;
  const int tm = blockIdx.x * 128;
  const int tn = blockIdx.y * 128;

  const int srow = lane >> 3;
  const int scol = ((lane & 7) ^ srow) * 8;
  const unsigned short* aptr = A + (size_t)(tm + 32 * w + srow) * 1024 + scol;
  const unsigned short* bptr = Bw + (size_t)(tn + 32 * w + srow) * 1024 + scol;
  unsigned short* lAw = &lA[(32 * w) * 64];
  unsigned short* lBw = &lB[(32 * w) * 64];

  const f32x4 zero = {0.f, 0.f, 0.f, 0.f};
  f32x4 acc[4][4];
#pragma unroll
  for (int i = 0; i < 4; ++i)
#pragma unroll
    for (int j = 0; j < 4; ++j) acc[i][j] = zero;

  for (int kb = 0; kb < 16; ++kb) {
    const int ko = kb * 64;
#pragma unroll
    for (int c = 0; c < 4; ++c) {
      gload_lds16(aptr + ko + c * 8 * 1024, lAw + c * 8 * 64);
      gload_lds16(bptr + ko + c * 8 * 1024, lBw + c * 8 * 64);
    }
    __syncthreads();
#pragma unroll
    for (int kk = 0; kk < 2; ++kk) {
      short8 af[4], bfr[4];
#pragma unroll
      for (int mi = 0; mi < 4; ++mi) {
        int r = 64 * wr + 16 * mi + (lane & 15);
        int slot = (kk * 4 + (lane >> 4)) ^ (r & 7);
        af[mi] = *(const short8*)&lA[r * 64 + slot * 8];
      }
#pragma unroll
      for (int ni = 0; ni < 4; ++ni) {
        int r = 64 * wcn + 16 * ni + (lane & 15);
        int slot = (kk * 4 + (lane >> 4)) ^ (r & 7);
        bfr[ni] = *(const short8*)&lB[r * 64 + slot * 8];
      }
#pragma unroll
      for (int mi = 0; mi < 4; ++mi)
#pragma unroll
        for (int ni = 0; ni < 4; ++ni)
          acc[mi][ni] = __builtin_amdgcn_mfma_f32_16x16x32_bf16(
              af[mi], bfr[ni], acc[mi][ni], 0, 0, 0);
    }
    __syncthreads();
  }

  const int g4 = (lane >> 4) * 4;
  const int c0 = lane & 15;
#pragma unroll
  for (int mi = 0; mi < 4; ++mi) {
#pragma unroll
    for (int ni = 0; ni < 4; ++ni) {
      const int colt = tn + 64 * wcn + 16 * ni + c0;
      const float bv = bias[colt];
#pragma unroll
      for (int j = 0; j < 4; ++j) {
        const int rowt = tm + 64 * wr + 16 * mi + g4 + j;
        const float v = acc[mi][ni][j] + bv;
        if constexpr (MODE == 0) {
          ((float*)outp)[(size_t)rowt * 1024 + colt] = v;
        } else if constexpr (MODE == 1) {
          const int i = rowt >> 1, b = rowt & 1, n = colt >> 6, d = colt & 63;
          ((unsigned short*)outp)[(((size_t)(b * 16 + n) * 2048 + i) << 6) + d] =
              f2bf(v * 0.1803368801111f);  // 1/8 * log2(e): exp2-direct scores
        } else if constexpr (MODE == 2) {
          const int jj = rowt >> 1, b = rowt & 1, n = colt >> 6, d = colt & 63;
          ((unsigned short*)outp)[(((size_t)(b * 16 + n) * 4096 + jj) << 6) + d] = f2bf(v);
        } else {
          const int jj = rowt >> 1, b = rowt & 1, n = colt >> 6, d = colt & 63;
          const int j6 = jj & 63;
          const int pos = (j6 & 3) | (((j6 >> 4) & 1) << 2) | (((j6 >> 2) & 3) << 3) |
                          (((j6 >> 5) & 1) << 5);
          ((unsigned short*)outp)[((size_t)(b * 16 + n) * 64 + d) * 4096 + (jj & ~63) + pos] =
              f2bf(v);
        }
      }
    }
  }
}

// ---------------------------------------------------------------------------
// Flash attention. Block = (head, 128-row q-tile): 512 threads / 8 waves,
// 16 q-rows per wave. Grid 512 = 2 blocks/CU (4 waves/SIMD).
// K/V staged as pairs of 64x64 sub-tiles (proven layout per sub-tile),
// double-buffered: stage next pair -> compute sub0, sub1 -> vmcnt(0) +
// s_barrier, fully unrolled (compile-time buffer indices).
// S^T = mfma(K,Q): lane holds 16 scores of query column i=lane&15.
// V pre-permuted so PV B-frag is one ds_read_b128. XCD map: f&7 = xcd.
__global__ __launch_bounds__(512, 4) void attn_kernel(
    const unsigned short* __restrict__ qh, const unsigned short* __restrict__ kh,
    const unsigned short* __restrict__ vt, unsigned short* __restrict__ vec) {
  __shared__ __align__(16) unsigned short kl[2][2][64 * 64];
  __shared__ __align__(16) unsigned short vl[2][2][64 * 64];
  const int tid = threadIdx.x;
  const int lane = tid & 63;
  const int w = tid >> 6;  // 0..7
  const int g = lane >> 4;
  const int l4 = lane & 15;
  // f = [qt(4) | head_lo(2) | xcd(3)]: per XCD, 4 heads x 16 q-tiles
  const int f = blockIdx.x;
  const int head = (f & 7) * 4 + ((f >> 3) & 3);
  const int qt = f >> 5;  // 0..15
  const int b = head >> 4, n = head & 15;
  const unsigned short* qbase = qh + ((size_t)head * 2048 + qt * 128 + 16 * w) * 64;
  const unsigned short* kbase = kh + (size_t)head * 4096 * 64;
  const unsigned short* vbase = vt + (size_t)head * 64 * 4096;

  // Q fragment: 16 rows per wave (A-layout of Q == B-layout of Q^T)
  short8 qf[2];
#pragma unroll
  for (int kk = 0; kk < 2; ++kk)
    qf[kk] = *(const short8*)&qbase[l4 * 64 + kk * 32 + g * 8];

  const f32x4 zero = {0.f, 0.f, 0.f, 0.f};
  f32x4 oacc[4];
#pragma unroll
  for (int nd = 0; nd < 4; ++nd) oacc[nd] = zero;
  float mrow = -3.0e38f;  // running max of column i=l4 (log2 units)
  float lrow = 0.f;       // full row denominator (reduced per sub-tile)

  const int srow = lane >> 3;
  const int scol = ((lane & 7) ^ srow) * 8;
  // each wave stages 8 rows (1 KB) of K and of V per 64-j sub-tile
  const unsigned short* kp = kbase + (size_t)(8 * w + srow) * 64 + scol;
  const unsigned short* vp = vbase + (size_t)(8 * w + srow) * 4096 + scol;

  // stage one pair (j-tiles 2jp, 2jp+1) into buffer bufi: 4 gloads/wave
  auto stage_pair = [&](int jp, int bufi) {
    gload_lds16(kp + (size_t)jp * 8192,        &kl[bufi][0][(8 * w) * 64]);
    gload_lds16(kp + (size_t)jp * 8192 + 4096, &kl[bufi][1][(8 * w) * 64]);
    gload_lds16(vp + jp * 128,                 &vl[bufi][0][(8 * w) * 64]);
    gload_lds16(vp + jp * 128 + 64,            &vl[bufi][1][(8 * w) * 64]);
  };

  // one proven 64-j sub-tile: QK^T -> online softmax (defer-max) -> P -> PV
  auto subtile = [&](const unsigned short* kbuf, const unsigned short* vbuf) {
    f32x4 s[4];
#pragma unroll
    for (int nj = 0; nj < 4; ++nj) s[nj] = zero;
    __builtin_amdgcn_s_setprio(1);
#pragma unroll
    for (int kk = 0; kk < 2; ++kk) {
      short8 bk[4];
#pragma unroll
      for (int nj = 0; nj < 4; ++nj) {
        int r = 16 * nj + l4;
        int slot = (kk * 4 + g) ^ (r & 7);
        bk[nj] = *(const short8*)&kbuf[r * 64 + slot * 8];
      }
#pragma unroll
      for (int nj = 0; nj < 4; ++nj)
        s[nj] = __builtin_amdgcn_mfma_f32_16x16x32_bf16(bk[nj], qf[kk], s[nj], 0, 0, 0);
    }
    __builtin_amdgcn_s_setprio(0);

    // online softmax per column i=l4 (proven defer-max numerics)
    {
      float a0 = fmaxf(fmaxf(s[0][0], s[0][1]), fmaxf(s[0][2], s[0][3]));
      float a1 = fmaxf(fmaxf(s[1][0], s[1][1]), fmaxf(s[1][2], s[1][3]));
      float a2 = fmaxf(fmaxf(s[2][0], s[2][1]), fmaxf(s[2][2], s[2][3]));
      float a3 = fmaxf(fmaxf(s[3][0], s[3][1]), fmaxf(s[3][2], s[3][3]));
      float pmax = fmaxf(fmaxf(a0, a1), fmaxf(a2, a3));
      pmax = fmaxf(pmax, __shfl_xor(pmax, 16));
      pmax = fmaxf(pmax, __shfl_xor(pmax, 32));
      if (!__all(pmax <= mrow + 8.f)) {  // defer-max (T13), log2 units
        const float mnew = fmaxf(mrow, pmax);
        const float sc = __builtin_amdgcn_exp2f(mrow - mnew);
        mrow = mnew;
        lrow *= sc;
        // broadcast sc from column-holder (lane i) to row-holders (rows 4g+reg)
#pragma unroll
        for (int reg = 0; reg < 4; ++reg) {
          const float scr = __shfl(sc, 4 * g + reg);
#pragma unroll
          for (int nd = 0; nd < 4; ++nd) oacc[nd][reg] *= scr;
        }
      }
      const float m = mrow;
      float rs = 0.f;
#pragma unroll
      for (int nj = 0; nj < 4; ++nj)
#pragma unroll
        for (int reg = 0; reg < 4; ++reg) {
          const float p = __builtin_amdgcn_exp2f(s[nj][reg] - m);
          s[nj][reg] = p;
          rs += p;
        }
      rs += __shfl_xor(rs, 16);
      rs += __shfl_xor(rs, 32);
      lrow += rs;
    }

    // pack P lane-locally: slot e of chunk kk2 -> j = 4g+(e&3)+16(e>>2)+32kk2
    short8 pa[2];
#pragma unroll
    for (int kk2 = 0; kk2 < 2; ++kk2) {
      union { unsigned int u[4]; short8 v; } t;
#pragma unroll
      for (int wd = 0; wd < 4; ++wd) {
        const int nj = (wd >> 1) + 2 * kk2;
        const int r0 = (wd & 1) * 2;
        t.u[wd] = cvtpk(s[nj][r0], s[nj][r0 + 1]);
      }
      pa[kk2] = t.v;
    }

    // O += P V; V rows pre-permuted so the 8 k-slots of (g,kk2) are one
    // contiguous 16B block (index g+4kk2, XOR row swizzle) -> ds_read_b128
    __builtin_amdgcn_s_setprio(1);
#pragma unroll
    for (int kk2 = 0; kk2 < 2; ++kk2) {
      short8 bv4[4];
#pragma unroll
      for (int nd = 0; nd < 4; ++nd) {
        const int r = 16 * nd + l4;
        const int blk = (g + 4 * kk2) ^ (r & 7);
        bv4[nd] = *(const short8*)&vbuf[r * 64 + blk * 8];
      }
#pragma unroll
      for (int nd = 0; nd < 4; ++nd)
        oacc[nd] = __builtin_amdgcn_mfma_f32_16x16x32_bf16(pa[kk2], bv4[nd], oacc[nd], 0, 0, 0);
    }
    __builtin_amdgcn_s_setprio(0);
  };

  // prologue: stage pair 0; drain (also retires qf loads)
  stage_pair(0, 0);
  asm volatile("s_waitcnt vmcnt(0)" ::: "memory");
  BARRIER_RAW();

  // 32 pairs, unrolled x2 so buffer indices are compile-time constants
  for (int t2 = 0; t2 < 16; ++t2) {
    // pair 2*t2 in buf 0; stage pair 2*t2+1 into buf 1
    stage_pair(2 * t2 + 1, 1);
    subtile(kl[0][0], vl[0][0]);
    subtile(kl[0][1], vl[0][1]);
    asm volatile("s_waitcnt vmcnt(0)" ::: "memory");
    BARRIER_RAW();
    // pair 2*t2+1 in buf 1; stage pair 2*t2+2 into buf 0
    if (t2 < 15) stage_pair(2 * t2 + 2, 0);
    subtile(kl[1][0], vl[1][0]);
    subtile(kl[1][1], vl[1][1]);
    if (t2 < 15) {
      asm volatile("s_waitcnt vmcnt(0)" ::: "memory");
      BARRIER_RAW();
    }
  }

  // epilogue: lrow is the full row sum; rows 4g+reg read it by shfl
#pragma unroll
  for (int reg = 0; reg < 4; ++reg) {
    const float lr = __shfl(lrow, 4 * g + reg);
    const float inv = 1.f / lr;
    const int i = qt * 128 + 16 * w + 4 * g + reg;
#pragma unroll
    for (int nd = 0; nd < 4; ++nd) {
      const int d = 16 * nd + l4;
      vec[(size_t)(i * 2 + b) * 1024 + n * 64 + d] = f2bf(oacc[nd][reg] * inv);
    }
  }
}

// ---------------------------------------------------------------------------
extern "C" void kernel_launch(void* const* d_in, const int* in_sizes, int n_in,
                              void* d_out, int out_size, void* d_ws, size_t ws_size,
                              hipStream_t stream) {
  (void)in_sizes; (void)n_in; (void)out_size; (void)ws_size;
  const float* q    = (const float*)d_in[0];
  const float* kv   = (const float*)d_in[1];
  const float* mem_ = (const float*)d_in[2];
  const float* wq   = (const float*)d_in[3];
  const float* bq   = (const float*)d_in[4];
  const float* wk   = (const float*)d_in[5];
  const float* bk   = (const float*)d_in[6];
  const float* wv   = (const float*)d_in[7];
  const float* bv   = (const float*)d_in[8];
  const float* wc   = (const float*)d_in[9];
  const float* bc   = (const float*)d_in[10];

  char* ws = (char*)d_ws;
  unsigned short* w_bf = (unsigned short*)(ws);                       // 8 MB: wq,wk,wv,wc
  unsigned short* a_bf = (unsigned short*)(ws + (8ull << 20));        // 8 MB: q bf16 [4096][1024]
  unsigned short* c_bf = (unsigned short*)(ws + (16ull << 20));       // 16 MB: concat(mem,kv)
  unsigned short* qhb  = (unsigned short*)(ws + (32ull << 20));       // 8 MB: [b][n][2048][64]
  unsigned short* khb  = (unsigned short*)(ws + (40ull << 20));       // 16 MB: [b][n][4096][64]
  unsigned short* vtb  = (unsigned short*)(ws + (56ull << 20));       // 16 MB: [b][n][64][pi(j)]
  unsigned short* vecb = a_bf;  // reuse (a_bf dead after Q projection)

  convert_all<<<8192, 256, 0, stream>>>(q, mem_, kv, wq, wk, wv, wc, a_bf, c_bf, w_bf);
  gemm_bt<1><<<dim3(32, 8), 256, 0, stream>>>(a_bf, w_bf,                bq, qhb);
  gemm_bt<2><<<dim3(64, 8), 256, 0, stream>>>(c_bf, w_bf + (1u << 20),   bk, khb);
  gemm_bt<3><<<dim3(64, 8), 256, 0, stream>>>(c_bf, w_bf + (2u << 20),   bv, vtb);
  attn_kernel<<<512, 512, 0, stream>>>(qhb, khb, vtb, vecb);
  gemm_bt<0><<<dim3(32, 8), 256, 0, stream>>>(vecb, w_bf + (3u << 20),   bc, d_out);
}

// Round 8
// 189.593 us; speedup vs baseline: 1.6512x; 1.0314x over previous
//
#include <hip/hip_runtime.h>

// XL-attention: out = (softmax(Qh Kh^T / 8) Vh) @ Wc^T + bc
// L=2048, B=2, M=2048 -> J=4096, D=1024, H=16, Dh=64.
// All matmuls in bf16 MFMA (16x16x32), f32 accumulate.
// Attention: swapped QK^T (S^T = K Q^T), in-register online softmax with
// defer-max (p = 2^(s-m) <= 2^8), in-register P. 4-wave blocks, 32 q-rows
// per wave (M=2): each K/V LDS fragment read feeds 2 MFMAs -> LDS port
// traffic halved (the measured bottleneck). Paired 64x64 sub-tiles,
// double-buffered, unrolled, setprio. l-reduction deferred to epilogue.
// V pre-permuted so the PV B-frag is one ds_read_b128.

using short8 = __attribute__((ext_vector_type(8))) short;
using f32x4  = __attribute__((ext_vector_type(4))) float;

#define DEV __device__ __forceinline__

DEV unsigned short f2bf(float f) {
  union { float f; unsigned int u; } x; x.f = f;
  unsigned int r = x.u + 0x7FFFu + ((x.u >> 16) & 1u);
  return (unsigned short)(r >> 16);
}

DEV unsigned int cvtpk(float lo, float hi) {
  unsigned int r;
  asm("v_cvt_pk_bf16_f32 %0, %1, %2" : "=v"(r) : "v"(lo), "v"(hi));
  return r;
}

DEV float max3f(float a, float b, float c) {
  float d;
  asm("v_max3_f32 %0, %1, %2, %3" : "=v"(d) : "v"(a), "v"(b), "v"(c));
  return d;
}

DEV void gload_lds16(const unsigned short* g, unsigned short* l) {
  __builtin_amdgcn_global_load_lds(
      (const __attribute__((address_space(1))) unsigned int*)g,
      (__attribute__((address_space(3))) unsigned int*)l, 16, 0, 0);
}

#define BARRIER_RAW()                      \
  do {                                     \
    __builtin_amdgcn_sched_barrier(0);     \
    __builtin_amdgcn_s_barrier();          \
    __builtin_amdgcn_sched_barrier(0);     \
  } while (0)

// ---------------------------------------------------------------------------
// f32 -> bf16 conversion of all inputs (q, concat(mem,kv), 4 weights)
__global__ __launch_bounds__(256) void convert_all(
    const float* __restrict__ q, const float* __restrict__ mem_,
    const float* __restrict__ kv, const float* __restrict__ wq,
    const float* __restrict__ wk, const float* __restrict__ wv,
    const float* __restrict__ wc, unsigned short* __restrict__ a_bf,
    unsigned short* __restrict__ c_bf, unsigned short* __restrict__ w_bf) {
  size_t u = (size_t)blockIdx.x * 256 + threadIdx.x;
  const float* src;
  unsigned short* dst;
  if (u < 524288u)        { src = q    + u * 8;                dst = a_bf + u * 8; }
  else if (u < 1048576u)  { src = mem_ + (u - 524288u) * 8;    dst = c_bf + (u - 524288u) * 8; }
  else if (u < 1572864u)  { src = kv   + (u - 1048576u) * 8;   dst = c_bf + 4194304u + (u - 1048576u) * 8; }
  else if (u < 1703936u)  { src = wq   + (u - 1572864u) * 8;   dst = w_bf + (u - 1572864u) * 8; }
  else if (u < 1835008u)  { src = wk   + (u - 1703936u) * 8;   dst = w_bf + 1048576u + (u - 1703936u) * 8; }
  else if (u < 1966080u)  { src = wv   + (u - 1835008u) * 8;   dst = w_bf + 2097152u + (u - 1835008u) * 8; }
  else                    { src = wc   + (u - 1966080u) * 8;   dst = w_bf + 3145728u + (u - 1966080u) * 8; }
  float4 v0 = ((const float4*)src)[0];
  float4 v1 = ((const float4*)src)[1];
  union { unsigned short us[8]; uint4 v; } o;
  o.us[0] = f2bf(v0.x); o.us[1] = f2bf(v0.y); o.us[2] = f2bf(v0.z); o.us[3] = f2bf(v0.w);
  o.us[4] = f2bf(v1.x); o.us[5] = f2bf(v1.y); o.us[6] = f2bf(v1.z); o.us[7] = f2bf(v1.w);
  *(uint4*)dst = o.v;
}

// ---------------------------------------------------------------------------
// C[M,1024] = A[M,1024] x Bw[1024,1024]^T (+bias). Bw is [N][K] (torch Linear).
// 128x128 tile, BK=64, 4 waves, 16x16x32 MFMA, XOR-swizzled LDS (rule #21).
// MODE 0: f32 out row-major (+bias)
// MODE 1: bf16 (acc+bias)*0.125*log2e -> qh[b][n][i][d]  (scores in log2 units)
// MODE 2: bf16 (acc+bias)            -> kh[b][n][j][d]
// MODE 3: bf16 (acc+bias)            -> vt[b][n][d][pi(j)]  (transposed V,
//         j permuted within each 64-group so attn PV frag is one b128 read)
template <int MODE>
__global__ __launch_bounds__(256, 2) void gemm_bt(
    const unsigned short* __restrict__ A, const unsigned short* __restrict__ Bw,
    const float* __restrict__ bias, void* __restrict__ outp) {
  __shared__ __align__(16) unsigned short lA[128 * 64];
  __shared__ __align__(16) unsigned short lB[128 * 64];
  const int tid = threadIdx.x;
  const int lane = tid & 63;
  const int w = tid >> 6;
  const int wr = w >> 1, wcn = w & 1;
  const int tm = blockIdx.x * 128;
  const int tn = blockIdx.y * 128;

  const int srow = lane >> 3;
  const int scol = ((lane & 7) ^ srow) * 8;
  const unsigned short* aptr = A + (size_t)(tm + 32 * w + srow) * 1024 + scol;
  const unsigned short* bptr = Bw + (size_t)(tn + 32 * w + srow) * 1024 + scol;
  unsigned short* lAw = &lA[(32 * w) * 64];
  unsigned short* lBw = &lB[(32 * w) * 64];

  const f32x4 zero = {0.f, 0.f, 0.f, 0.f};
  f32x4 acc[4][4];
#pragma unroll
  for (int i = 0; i < 4; ++i)
#pragma unroll
    for (int j = 0; j < 4; ++j) acc[i][j] = zero;

  for (int kb = 0; kb < 16; ++kb) {
    const int ko = kb * 64;
#pragma unroll
    for (int c = 0; c < 4; ++c) {
      gload_lds16(aptr + ko + c * 8 * 1024, lAw + c * 8 * 64);
      gload_lds16(bptr + ko + c * 8 * 1024, lBw + c * 8 * 64);
    }
    __syncthreads();
#pragma unroll
    for (int kk = 0; kk < 2; ++kk) {
      short8 af[4], bfr[4];
#pragma unroll
      for (int mi = 0; mi < 4; ++mi) {
        int r = 64 * wr + 16 * mi + (lane & 15);
        int slot = (kk * 4 + (lane >> 4)) ^ (r & 7);
        af[mi] = *(const short8*)&lA[r * 64 + slot * 8];
      }
#pragma unroll
      for (int ni = 0; ni < 4; ++ni) {
        int r = 64 * wcn + 16 * ni + (lane & 15);
        int slot = (kk * 4 + (lane >> 4)) ^ (r & 7);
        bfr[ni] = *(const short8*)&lB[r * 64 + slot * 8];
      }
#pragma unroll
      for (int mi = 0; mi < 4; ++mi)
#pragma unroll
        for (int ni = 0; ni < 4; ++ni)
          acc[mi][ni] = __builtin_amdgcn_mfma_f32_16x16x32_bf16(
              af[mi], bfr[ni], acc[mi][ni], 0, 0, 0);
    }
    __syncthreads();
  }

  const int g4 = (lane >> 4) * 4;
  const int c0 = lane & 15;
#pragma unroll
  for (int mi = 0; mi < 4; ++mi) {
#pragma unroll
    for (int ni = 0; ni < 4; ++ni) {
      const int colt = tn + 64 * wcn + 16 * ni + c0;
      const float bv = bias[colt];
#pragma unroll
      for (int j = 0; j < 4; ++j) {
        const int rowt = tm + 64 * wr + 16 * mi + g4 + j;
        const float v = acc[mi][ni][j] + bv;
        if constexpr (MODE == 0) {
          ((float*)outp)[(size_t)rowt * 1024 + colt] = v;
        } else if constexpr (MODE == 1) {
          const int i = rowt >> 1, b = rowt & 1, n = colt >> 6, d = colt & 63;
          ((unsigned short*)outp)[(((size_t)(b * 16 + n) * 2048 + i) << 6) + d] =
              f2bf(v * 0.1803368801111f);  // 1/8 * log2(e): exp2-direct scores
        } else if constexpr (MODE == 2) {
          const int jj = rowt >> 1, b = rowt & 1, n = colt >> 6, d = colt & 63;
          ((unsigned short*)outp)[(((size_t)(b * 16 + n) * 4096 + jj) << 6) + d] = f2bf(v);
        } else {
          const int jj = rowt >> 1, b = rowt & 1, n = colt >> 6, d = colt & 63;
          const int j6 = jj & 63;
          const int pos = (j6 & 3) | (((j6 >> 4) & 1) << 2) | (((j6 >> 2) & 3) << 3) |
                          (((j6 >> 5) & 1) << 5);
          ((unsigned short*)outp)[((size_t)(b * 16 + n) * 64 + d) * 4096 + (jj & ~63) + pos] =
              f2bf(v);
        }
      }
    }
  }
}

// ---------------------------------------------------------------------------
// Flash attention. Block = (head, 128-row q-tile): 256 threads / 4 waves,
// 32 q-rows per wave (mi=0,1). Grid 512 = 2 blocks/CU (8 waves/CU).
// Each bk/bv4 LDS fragment feeds BOTH mi MFMAs (halved LDS traffic).
// K/V staged as pairs of 64x64 sub-tiles, double-buffered, unrolled.
// S^T = mfma(K,Q): lane holds j=16nj+4g+reg of columns i=16mi+l4.
// Defer-max softmax; l kept as per-lane partials, reduced in epilogue.
// V pre-permuted so PV B-frag is one ds_read_b128. XCD map: f&7 = xcd.
__global__ __launch_bounds__(256, 2) void attn_kernel(
    const unsigned short* __restrict__ qh, const unsigned short* __restrict__ kh,
    const unsigned short* __restrict__ vt, unsigned short* __restrict__ vec) {
  __shared__ __align__(16) unsigned short kl[2][2][64 * 64];
  __shared__ __align__(16) unsigned short vl[2][2][64 * 64];
  const int tid = threadIdx.x;
  const int lane = tid & 63;
  const int w = tid >> 6;  // 0..3
  const int g = lane >> 4;
  const int l4 = lane & 15;
  // f = [qt(4) | head_lo(2) | xcd(3)]: per XCD, 4 heads x 16 q-tiles
  const int f = blockIdx.x;
  const int head = (f & 7) * 4 + ((f >> 3) & 3);
  const int qt = f >> 5;  // 0..15
  const int b = head >> 4, n = head & 15;
  const unsigned short* qbase = qh + ((size_t)head * 2048 + qt * 128 + 32 * w) * 64;
  const unsigned short* kbase = kh + (size_t)head * 4096 * 64;
  const unsigned short* vbase = vt + (size_t)head * 64 * 4096;

  // Q fragments: 32 rows per wave (A-layout of Q == B-layout of Q^T)
  short8 qf[2][2];
#pragma unroll
  for (int mi = 0; mi < 2; ++mi)
#pragma unroll
    for (int kk = 0; kk < 2; ++kk)
      qf[mi][kk] = *(const short8*)&qbase[(16 * mi + l4) * 64 + kk * 32 + g * 8];

  const f32x4 zero = {0.f, 0.f, 0.f, 0.f};
  f32x4 oacc[2][4];
#pragma unroll
  for (int mi = 0; mi < 2; ++mi)
#pragma unroll
    for (int nd = 0; nd < 4; ++nd) oacc[mi][nd] = zero;
  float mrow[2] = {-3.0e38f, -3.0e38f};  // running max of col i=16mi+l4 (log2)
  float lsum[2] = {0.f, 0.f};            // per-lane partial denominators

  const int srow = lane >> 3;
  const int scol = ((lane & 7) ^ srow) * 8;
  // each wave stages 16 rows (2 KB) of K and of V per 64-j sub-tile
  const unsigned short* kp = kbase + (size_t)(16 * w + srow) * 64 + scol;
  const unsigned short* vp = vbase + (size_t)(16 * w + srow) * 4096 + scol;

  // stage one pair (j-tiles 2jp, 2jp+1) into buffer bufi: 8 gloads/wave
  auto stage_pair = [&](int jp, int bufi) {
#pragma unroll
    for (int sub = 0; sub < 2; ++sub) {
      gload_lds16(kp + (size_t)jp * 8192 + sub * 4096,
                  &kl[bufi][sub][(16 * w) * 64]);
      gload_lds16(kp + (size_t)jp * 8192 + sub * 4096 + 8 * 64,
                  &kl[bufi][sub][(16 * w + 8) * 64]);
      gload_lds16(vp + jp * 128 + sub * 64, &vl[bufi][sub][(16 * w) * 64]);
      gload_lds16(vp + jp * 128 + sub * 64 + 8 * 4096,
                  &vl[bufi][sub][(16 * w + 8) * 64]);
    }
  };

  // one 64-j sub-tile for both mi: QK^T -> defer-max softmax -> P -> PV
  auto subtile = [&](const unsigned short* kbuf, const unsigned short* vbuf) {
    f32x4 s[2][4];
#pragma unroll
    for (int mi = 0; mi < 2; ++mi)
#pragma unroll
      for (int nj = 0; nj < 4; ++nj) s[mi][nj] = zero;
    __builtin_amdgcn_s_setprio(1);
#pragma unroll
    for (int kk = 0; kk < 2; ++kk) {
      short8 bk[4];
#pragma unroll
      for (int nj = 0; nj < 4; ++nj) {
        int r = 16 * nj + l4;
        int slot = (kk * 4 + g) ^ (r & 7);
        bk[nj] = *(const short8*)&kbuf[r * 64 + slot * 8];
      }
#pragma unroll
      for (int mi = 0; mi < 2; ++mi)
#pragma unroll
        for (int nj = 0; nj < 4; ++nj)
          s[mi][nj] = __builtin_amdgcn_mfma_f32_16x16x32_bf16(bk[nj], qf[mi][kk], s[mi][nj], 0, 0, 0);
    }
    __builtin_amdgcn_s_setprio(0);

    // per-mi 16-max via v_max3, then joint pmax (one cross-lane pair)
    float pm[2];
#pragma unroll
    for (int mi = 0; mi < 2; ++mi) {
      float t0 = max3f(s[mi][0][0], s[mi][0][1], s[mi][0][2]);
      float t1 = max3f(s[mi][0][3], s[mi][1][0], s[mi][1][1]);
      float t2 = max3f(s[mi][1][2], s[mi][1][3], s[mi][2][0]);
      float t3 = max3f(s[mi][2][1], s[mi][2][2], s[mi][2][3]);
      float t4 = max3f(s[mi][3][0], s[mi][3][1], s[mi][3][2]);
      float p5 = max3f(t0, t1, t2);
      p5 = max3f(p5, t3, t4);
      pm[mi] = fmaxf(p5, s[mi][3][3]);
    }
    float pj = fmaxf(pm[0], pm[1]);
    pj = fmaxf(pj, __shfl_xor(pj, 16));
    pj = fmaxf(pj, __shfl_xor(pj, 32));
    if (!__all(pj <= fminf(mrow[0], mrow[1]) + 8.f)) {  // defer-max (T13)
#pragma unroll
      for (int mi = 0; mi < 2; ++mi) {
        const float mnew = fmaxf(mrow[mi], pj);  // joint max: >= per-col max, safe
        const float sc = __builtin_amdgcn_exp2f(mrow[mi] - mnew);
        mrow[mi] = mnew;
        lsum[mi] *= sc;  // per-lane partial: no shuffle needed
        // broadcast sc from column-holder (lane i) to row-holders (rows 4g+reg)
#pragma unroll
        for (int reg = 0; reg < 4; ++reg) {
          const float scr = __shfl(sc, 4 * g + reg);
#pragma unroll
          for (int nd = 0; nd < 4; ++nd) oacc[mi][nd][reg] *= scr;
        }
      }
    }

    short8 pa[2][2];
#pragma unroll
    for (int mi = 0; mi < 2; ++mi) {
      const float m = mrow[mi];
      float rs = 0.f;
#pragma unroll
      for (int nj = 0; nj < 4; ++nj)
#pragma unroll
        for (int reg = 0; reg < 4; ++reg) {
          const float p = __builtin_amdgcn_exp2f(s[mi][nj][reg] - m);
          s[mi][nj][reg] = p;
          rs += p;
        }
      lsum[mi] += rs;  // per-lane partial; cross-lane reduce in epilogue
      // pack P lane-locally: slot e of chunk kk2 -> j = 4g+(e&3)+16(e>>2)+32kk2
#pragma unroll
      for (int kk2 = 0; kk2 < 2; ++kk2) {
        union { unsigned int u[4]; short8 v; } t;
#pragma unroll
        for (int wd = 0; wd < 4; ++wd) {
          const int nj = (wd >> 1) + 2 * kk2;
          const int r0 = (wd & 1) * 2;
          t.u[wd] = cvtpk(s[mi][nj][r0], s[mi][nj][r0 + 1]);
        }
        pa[mi][kk2] = t.v;
      }
    }

    // O += P V; V rows pre-permuted so the 8 k-slots of (g,kk2) are one
    // contiguous 16B block; bv4 shared by both mi (LDS amortization)
    __builtin_amdgcn_s_setprio(1);
#pragma unroll
    for (int kk2 = 0; kk2 < 2; ++kk2) {
      short8 bv4[4];
#pragma unroll
      for (int nd = 0; nd < 4; ++nd) {
        const int r = 16 * nd + l4;
        const int blk = (g + 4 * kk2) ^ (r & 7);
        bv4[nd] = *(const short8*)&vbuf[r * 64 + blk * 8];
      }
#pragma unroll
      for (int mi = 0; mi < 2; ++mi)
#pragma unroll
        for (int nd = 0; nd < 4; ++nd)
          oacc[mi][nd] = __builtin_amdgcn_mfma_f32_16x16x32_bf16(pa[mi][kk2], bv4[nd], oacc[mi][nd], 0, 0, 0);
    }
    __builtin_amdgcn_s_setprio(0);
  };

  // prologue: stage pair 0; drain (also retires qf loads)
  stage_pair(0, 0);
  asm volatile("s_waitcnt vmcnt(0)" ::: "memory");
  BARRIER_RAW();

  // 32 pairs, unrolled x2 so buffer indices are compile-time constants
  for (int t2 = 0; t2 < 16; ++t2) {
    stage_pair(2 * t2 + 1, 1);
    subtile(kl[0][0], vl[0][0]);
    subtile(kl[0][1], vl[0][1]);
    asm volatile("s_waitcnt vmcnt(0)" ::: "memory");
    BARRIER_RAW();
    if (t2 < 15) stage_pair(2 * t2 + 2, 0);
    subtile(kl[1][0], vl[1][0]);
    subtile(kl[1][1], vl[1][1]);
    if (t2 < 15) {
      asm volatile("s_waitcnt vmcnt(0)" ::: "memory");
      BARRIER_RAW();
    }
  }

  // epilogue: reduce per-lane l partials over the 4 g-lanes of each column,
  // then rows 4g+reg read their column's l by shfl
#pragma unroll
  for (int mi = 0; mi < 2; ++mi) {
    float l = lsum[mi];
    l += __shfl_xor(l, 16);
    l += __shfl_xor(l, 32);
#pragma unroll
    for (int reg = 0; reg < 4; ++reg) {
      const float lr = __shfl(l, 4 * g + reg);
      const float inv = 1.f / lr;
      const int i = qt * 128 + 32 * w + 16 * mi + 4 * g + reg;
#pragma unroll
      for (int nd = 0; nd < 4; ++nd) {
        const int d = 16 * nd + l4;
        vec[(size_t)(i * 2 + b) * 1024 + n * 64 + d] = f2bf(oacc[mi][nd][reg] * inv);
      }
    }
  }
}

// ---------------------------------------------------------------------------
extern "C" void kernel_launch(void* const* d_in, const int* in_sizes, int n_in,
                              void* d_out, int out_size, void* d_ws, size_t ws_size,
                              hipStream_t stream) {
  (void)in_sizes; (void)n_in; (void)out_size; (void)ws_size;
  const float* q    = (const float*)d_in[0];
  const float* kv   = (const float*)d_in[1];
  const float* mem_ = (const float*)d_in[2];
  const float* wq   = (const float*)d_in[3];
  const float* bq   = (const float*)d_in[4];
  const float* wk   = (const float*)d_in[5];
  const float* bk   = (const float*)d_in[6];
  const float* wv   = (const float*)d_in[7];
  const float* bv   = (const float*)d_in[8];
  const float* wc   = (const float*)d_in[9];
  const float* bc   = (const float*)d_in[10];

  char* ws = (char*)d_ws;
  unsigned short* w_bf = (unsigned short*)(ws);                       // 8 MB: wq,wk,wv,wc
  unsigned short* a_bf = (unsigned short*)(ws + (8ull << 20));        // 8 MB: q bf16 [4096][1024]
  unsigned short* c_bf = (unsigned short*)(ws + (16ull << 20));       // 16 MB: concat(mem,kv)
  unsigned short* qhb  = (unsigned short*)(ws + (32ull << 20));       // 8 MB: [b][n][2048][64]
  unsigned short* khb  = (unsigned short*)(ws + (40ull << 20));       // 16 MB: [b][n][4096][64]
  unsigned short* vtb  = (unsigned short*)(ws + (56ull << 20));       // 16 MB: [b][n][64][pi(j)]
  unsigned short* vecb = a_bf;  // reuse (a_bf dead after Q projection)

  convert_all<<<8192, 256, 0, stream>>>(q, mem_, kv, wq, wk, wv, wc, a_bf, c_bf, w_bf);
  gemm_bt<1><<<dim3(32, 8), 256, 0, stream>>>(a_bf, w_bf,                bq, qhb);
  gemm_bt<2><<<dim3(64, 8), 256, 0, stream>>>(c_bf, w_bf + (1u << 20),   bk, khb);
  gemm_bt<3><<<dim3(64, 8), 256, 0, stream>>>(c_bf, w_bf + (2u << 20),   bv, vtb);
  attn_kernel<<<512, 256, 0, stream>>>(qhb, khb, vtb, vecb);
  gemm_bt<0><<<dim3(32, 8), 256, 0, stream>>>(vecb, w_bf + (3u << 20),   bc, d_out);
}